// Round 5
// baseline (490.996 us; speedup 1.0000x reference)
//
#include <hip/hip_runtime.h>
#include <math.h>

#define NU_N 200000
#define NS_N 50000
#define E_N  1000000
#define M_N  100000
#define NUBG 782   // ceil(NU/256) gemm blocks
#define NSBG 196   // ceil(NS/256)

// ---- CSR build (2-level LDS counting sort) geometry ----
#define CH_E 2048      // edges per chunk
#define NCH  489       // ceil(E/CH_E)
#define NBKT 391       // coarse buckets per side (users: node>>9, sellers: node>>7)
#define CM   191199    // NBKT*NCH cmat entries per side
#define NCB  747       // ceil(CM/256) scan blocks per side

typedef __attribute__((ext_vector_type(8))) short short8;
typedef __attribute__((ext_vector_type(16))) float f32x16;
typedef unsigned short ushort_t;
typedef unsigned int uint_t;

// ---- workspace layout (bytes), ~174 MB ----
static constexpr size_t OFF_AGGU  = 0;             // NU x 128 bf16 (L1: stride 64, L2: 128)
                                                   // [ hosts tmpU|tmpS pair arrays (16 MB) pre-gather1 ]
static constexpr size_t OFF_AGGS  = 51200000;      // NS x 128 bf16 (L1: stride 80, L2: 128)
                                                   // [ hosts cmat arrays (3.1 MB) pre-gather1 ]
static constexpr size_t OFF_U     = 64000000;      // (NU+1) x 128 bf16 (+zero pad row)
                                                   // [ first 6.4 MB hosts oh12 pre-gemm1 ]
static constexpr size_t OFF_S     = 115200256;     // (NS+1) x 128 bf16
static constexpr size_t OFF_XU16  = 128000512;     // (NU+1) x 64 bf16
static constexpr size_t OFF_XS16  = 153600640;     // (NS+1) x 64 bf16
static constexpr size_t OFF_TBL27 = 160000768;     // 27 x 128 f32
static constexpr size_t OFF_Z1U   = 160014592;     // K=128 swizzled bf16
static constexpr size_t OFF_Z1S   = 160047360;     // K=144 (64 xu | 9 age | 3 gen | 4 pad | 64 self)
static constexpr size_t OFF_Z2U   = 160084224;     // K=256
static constexpr size_t OFF_Z2S   = 160149760;     // K=256
static constexpr size_t OFF_RPU   = 160215296;     // (NU+1) int
static constexpr size_t OFF_RPS   = 161015312;     // (NS+1) int
static constexpr size_t OFF_CSRU  = 161215328;     // (E+8) int
static constexpr size_t OFF_CSRS  = 165215360;     // (E+8) int
static constexpr size_t OFF_PART  = 173615392;     // 2 x 1024 int

// cmat/tmp aliases
static constexpr size_t OFF_TMPU = OFF_AGGU;                 // E x int2
static constexpr size_t OFF_TMPS = OFF_AGGU + 8000000;       // E x int2
static constexpr size_t OFF_CMU  = OFF_AGGS;                 // CM ints
static constexpr size_t OFF_CMS  = OFF_AGGS + 764800;
static constexpr size_t OFF_CMUS = OFF_AGGS + 1529600;
static constexpr size_t OFF_CMSS = OFF_AGGS + 2294400;

__device__ inline ushort_t f2bf(float f) {
  union { float f; uint_t u; } c; c.f = f;
  uint_t r = (c.u + 0x7FFFu + ((c.u >> 16) & 1u)) >> 16;
  return (ushort_t)r;
}
__device__ inline float u2f(uint_t u) {
  union { uint_t u; float f; } c; c.u = u;
  return c.f;
}
__device__ inline float bf2f(uint_t u) { return u2f(u << 16); }

// ===================== CSR build: 2-level LDS counting sort, 0 global atomics ====
// Pass 1: per-chunk LDS histogram over NBKT coarse buckets -> cmat[b][c].
__global__ void hist_lds_k(const int* __restrict__ du, const int* __restrict__ ds,
                           int* __restrict__ cmatU, int* __restrict__ cmatS) {
  __shared__ int h[NBKT];
  int side = blockIdx.x >= NCH;
  int c = side ? blockIdx.x - NCH : blockIdx.x;
  const int* nd = side ? ds : du;
  int shift = side ? 7 : 9;
  int* cm = side ? cmatS : cmatU;
  for (int i = threadIdx.x; i < NBKT; i += 256) h[i] = 0;
  __syncthreads();
  int e0 = c * CH_E, e1 = min(E_N, e0 + CH_E);
  for (int e = e0 + (int)threadIdx.x; e < e1; e += 256)
    atomicAdd(&h[nd[e] >> shift], 1);
  __syncthreads();
  for (int b = threadIdx.x; b < NBKT; b += 256) cm[b * NCH + c] = h[b];
}

// 3-phase exclusive scan over cmat (bucket-major), both sides.
__global__ void scan1_k(const int* __restrict__ cmU, const int* __restrict__ cmS,
                        int* __restrict__ outU, int* __restrict__ outS,
                        int* __restrict__ part) {
  __shared__ int s[256];
  int blk = blockIdx.x;
  const int* in; int* out; int* pp;
  if (blk < NCB) { in = cmU; out = outU; pp = part; }
  else { blk -= NCB; in = cmS; out = outS; pp = part + 1024; }
  int t = threadIdx.x;
  int idx = blk * 256 + t;
  int v = (idx > 0 && idx <= CM) ? in[idx - 1] : 0;
  s[t] = v;
  __syncthreads();
  for (int off = 1; off < 256; off <<= 1) {
    int x = (t >= off) ? s[t - off] : 0;
    __syncthreads();
    s[t] += x;
    __syncthreads();
  }
  if (idx < CM) out[idx] = s[t];
  if (t == 255) pp[blk] = s[255];
}

__global__ void scan2_k(int* __restrict__ part) {
  __shared__ int s[1024];
  int* pp = part + blockIdx.x * 1024;
  int nb = NCB;
  int t = threadIdx.x;
  int v = (t < nb) ? pp[t] : 0;
  s[t] = v;
  __syncthreads();
  for (int off = 1; off < 1024; off <<= 1) {
    int x = (t >= off) ? s[t - off] : 0;
    __syncthreads();
    s[t] += x;
    __syncthreads();
  }
  if (t < nb) pp[t] = s[t] - v;  // exclusive
}

__global__ void scan3_k(int* __restrict__ outU, int* __restrict__ outS,
                        const int* __restrict__ part) {
  int blk = blockIdx.x;
  int* out; const int* pp;
  if (blk < NCB) { out = outU; pp = part; }
  else { blk -= NCB; out = outS; pp = part + 1024; }
  int idx = blk * 256 + threadIdx.x;
  if (idx < CM) out[idx] += pp[blk];
}

// Pass 2: per-chunk scatter to bucket-major tmp pairs (node, value).
__global__ void scatter_k(const int* __restrict__ du, const int* __restrict__ ds,
                          const int* __restrict__ su, const int* __restrict__ ss,
                          const int* __restrict__ cmUs, const int* __restrict__ cmSs,
                          int2* __restrict__ tmpU, int2* __restrict__ tmpS) {
  __shared__ int cur[NBKT];
  int side = blockIdx.x >= NCH;
  int c = side ? blockIdx.x - NCH : blockIdx.x;
  const int* nd = side ? ds : du;
  const int* vv = side ? su : ss;
  const int* cms = side ? cmSs : cmUs;
  int2* tmp = side ? tmpS : tmpU;
  int shift = side ? 7 : 9;
  for (int b = threadIdx.x; b < NBKT; b += 256) cur[b] = cms[b * NCH + c];
  __syncthreads();
  int e0 = c * CH_E, e1 = min(E_N, e0 + CH_E);
  for (int e = e0 + (int)threadIdx.x; e < e1; e += 256) {
    int node = nd[e];
    int pos = atomicAdd(&cur[node >> shift], 1);
    int2 p; p.x = node; p.y = vv[e];
    tmp[pos] = p;
  }
}

// Pass 3: one block per bucket: exact LDS hist + scan -> rowptr + final CSR.
__global__ void build_k(const int* __restrict__ cmUs, const int* __restrict__ cmSs,
                        const int2* __restrict__ tmpU, const int2* __restrict__ tmpS,
                        int* __restrict__ rpU, int* __restrict__ rpS,
                        int* __restrict__ csrU, int* __restrict__ csrS) {
  __shared__ int cnt[512];
  __shared__ int s2[256];
  __shared__ int base[512];
  int side = blockIdx.x >= NBKT;
  int b = side ? blockIdx.x - NBKT : blockIdx.x;
  const int* cms = side ? cmSs : cmUs;
  const int2* tmp = side ? tmpS : tmpU;
  int* rp = side ? rpS : rpU;
  int* csr = side ? csrS : csrU;
  int nper = side ? 128 : 512;
  int nn = side ? NS_N : NU_N;
  int t = threadIdx.x;
  int start = cms[b * NCH];
  int end = (b + 1 < NBKT) ? cms[(b + 1) * NCH] : E_N;
  cnt[t] = 0; cnt[t + 256] = 0;
  __syncthreads();
  int nbase = b * nper;
  for (int i = start + t; i < end; i += 256) atomicAdd(&cnt[tmp[i].x - nbase], 1);
  __syncthreads();
  int a0 = cnt[2 * t], a1 = cnt[2 * t + 1];
  s2[t] = a0 + a1;
  __syncthreads();
  int v = s2[t];
  for (int off = 1; off < 256; off <<= 1) {
    int x = (t >= off) ? s2[t - off] : 0;
    __syncthreads();
    s2[t] += x;
    __syncthreads();
  }
  int ex = s2[t] - v;
  base[2 * t] = start + ex;
  base[2 * t + 1] = start + ex + a0;
  __syncthreads();
  for (int i = t; i < nper; i += 256) {
    int node = nbase + i;
    if (node < nn) rp[node] = base[i];
  }
  if (b == NBKT - 1 && t == 0) rp[nn] = E_N;
  __syncthreads();  // rowptr reads of base[] complete before cursors mutate
  for (int i = start + t; i < end; i += 256) {
    int2 p = tmp[i];
    int pos = atomicAdd(&base[p.x - nbase], 1);
    csr[pos] = p.y;
  }
}

// ===================== merged prep: bf16 feats + pads + tbl27 + oh12 + swizzles ====
__global__ void prep_all_k(const float* __restrict__ xu, const float* __restrict__ xs,
                           const int* __restrict__ x1, const float* __restrict__ age,
                           const float* __restrict__ gen,
                           const float* __restrict__ W1ul, const float* __restrict__ W1ur,
                           const float* __restrict__ W1sl, const float* __restrict__ W1sr,
                           const float* __restrict__ W2ul, const float* __restrict__ W2ur,
                           const float* __restrict__ W2sl, const float* __restrict__ W2sr,
                           ushort_t* __restrict__ xu16, ushort_t* __restrict__ xs16,
                           ushort_t* __restrict__ ub, ushort_t* __restrict__ sb,
                           ushort_t* __restrict__ oh12,
                           float* __restrict__ tbl27,
                           ushort_t* __restrict__ z1u, ushort_t* __restrict__ z1s,
                           ushort_t* __restrict__ z2u, ushort_t* __restrict__ z2s) {
  int t = blockIdx.x * 256 + threadIdx.x;
  if (t < 4000000) {  // xu16 (3.2M float4s) then xs16 (800k)
    const float* src = (t < 3200000) ? xu : xs;
    ushort_t* dst = (t < 3200000) ? xu16 : xs16;
    int i = (t < 3200000) ? t : t - 3200000;
    float4 v = ((const float4*)src)[i];
    uint2 o;
    o.x = (uint_t)f2bf(v.x) | ((uint_t)f2bf(v.y) << 16);
    o.y = (uint_t)f2bf(v.z) | ((uint_t)f2bf(v.w) << 16);
    ((uint2*)dst)[i] = o;
  } else if (t < 4000100) {  // zero pad rows (incl. oh12 pad row)
    int t3 = t - 4000000;
    uint2 z; z.x = 0u; z.y = 0u;
    if (t3 < 16)       ((uint2*)xu16)[NU_N * 16 + t3] = z;
    else if (t3 < 32)  ((uint2*)xs16)[NS_N * 16 + (t3 - 16)] = z;
    else if (t3 < 64)  ((uint2*)ub)[NU_N * 32 + (t3 - 32)] = z;
    else if (t3 < 96)  ((uint2*)sb)[NS_N * 32 + (t3 - 64)] = z;
    else               ((uint2*)oh12)[NU_N * 4 + (t3 - 96)] = z;
  } else if (t < 4003556) {  // tbl27: 27 x 128
    int i = t - 4000100;
    int tt = i >> 7, j = i & 127;
    int a = tt / 3, g = tt % 3;
    float acc = 0.f;
    for (int k = 0; k < 32; ++k) acc += age[a * 32 + k] * W1ur[k * 128 + j];
    for (int k = 0; k < 32; ++k) acc += gen[g * 32 + k] * W1ur[(32 + k) * 128 + j];
    tbl27[i] = acc;
  } else if (t < 4019940) {  // z1u: K=128 (W1ul 64 | W1ur[64:128])
    int i = t - 4003556;
    int j = i & 7, lane = (i >> 3) & 63, rest = i >> 9;
    int kt = rest % 8, ct = rest / 8;
    int k = kt * 16 + ((lane >> 5) << 3) + j;
    int n = ct * 32 + (lane & 31);
    float v = (k < 64) ? W1ul[k * 128 + n] : W1ur[k * 128 + n];
    z1u[i] = f2bf(v);
  } else if (t < 4038372) {  // z1s: K=144 (W1sl[64:128] | ageW 9 | genW 3 | 0 x4 | W1sr 64)
    int i = t - 4019940;
    int j = i & 7, lane = (i >> 3) & 63, rest = i >> 9;
    int kt = rest % 9, ct = rest / 9;
    int k = kt * 16 + ((lane >> 5) << 3) + j;
    int n = ct * 32 + (lane & 31);
    float v;
    if (k < 64) v = W1sl[(64 + k) * 128 + n];
    else if (k < 73) {
      int a = k - 64; v = 0.f;
      for (int kk = 0; kk < 32; ++kk) v += age[a * 32 + kk] * W1sl[kk * 128 + n];
    } else if (k < 76) {
      int g = k - 73; v = 0.f;
      for (int kk = 0; kk < 32; ++kk) v += gen[g * 32 + kk] * W1sl[(32 + kk) * 128 + n];
    } else if (k < 80) v = 0.f;
    else v = W1sr[(k - 80) * 128 + n];
    z1s[i] = f2bf(v);
  } else if (t < 4103908) {  // z2u then z2s: K=256
    int i = t - 4038372;
    const float *Wl, *Wr; ushort_t* dst;
    if (i < 32768) { Wl = W2ul; Wr = W2ur; dst = z2u; }
    else { Wl = W2sl; Wr = W2sr; dst = z2s; i -= 32768; }
    int j = i & 7, lane = (i >> 3) & 63, rest = i >> 9;
    int kt = rest % 16, ct = rest / 16;
    int k = kt * 16 + ((lane >> 5) << 3) + j;
    int n = ct * 32 + (lane & 31);
    float v = (k < 128) ? Wl[k * 128 + n] : Wr[(k - 128) * 128 + n];
    dst[i] = f2bf(v);
  } else if (t < 4303908) {  // oh12: NU x 16 bf16 one-hot(age)|one-hot(gen)|4 zeros
    int r = t - 4103908;
    int2 ag = ((const int2*)x1)[r];
    uint_t wds[8];
#pragma unroll
    for (int ww = 0; ww < 8; ++ww) {
      int d0 = 2 * ww, d1 = 2 * ww + 1;
      uint_t lo = ((d0 == ag.x) || (d0 == 9 + ag.y)) ? 0x3F80u : 0u;
      uint_t hi = ((d1 == ag.x) || (d1 == 9 + ag.y)) ? 0x3F80u : 0u;
      wds[ww] = lo | (hi << 16);
    }
    uint4* orow = (uint4*)(oh12 + (size_t)r * 16);
    uint4 o0; o0.x = wds[0]; o0.y = wds[1]; o0.z = wds[2]; o0.w = wds[3];
    uint4 o1; o1.x = wds[4]; o1.y = wds[5]; o1.z = wds[6]; o1.w = wds[7];
    orow[0] = o0;
    orow[1] = o1;
  }
}

// ===================== group-per-node gather core (dot2 + depth-8 pipeline) =====
// v_dot2_f32_bf16: acc += u.lo*sel.lo + u.hi*sel.hi (bf16 widened to f32, exact
// for sel in {1.0, 0.0}). SEL_LO=0x00003F80 adds the low bf16; SEL_HI=0x3F800000
// adds the high. One instruction replaces unpack(shl/and)+v_add_f32.
__device__ __forceinline__ void dot2acc(float& a, uint_t u, uint_t sel) {
  asm("v_dot2_f32_bf16 %0, %1, %2, %0" : "+v"(a) : "v"(u), "v"(sel));
}
#define DACC8(V)                                             \
  dot2acc(acc[0], V.x, SEL_LO); dot2acc(acc[1], V.x, SEL_HI);\
  dot2acc(acc[2], V.y, SEL_LO); dot2acc(acc[3], V.y, SEL_HI);\
  dot2acc(acc[4], V.z, SEL_LO); dot2acc(acc[5], V.z, SEL_HI);\
  dot2acc(acc[6], V.w, SEL_LO); dot2acc(acc[7], V.w, SEL_HI);

// One G-lane group owns one node; lane c owns uint4 #c of the output row.
// Depth-8 branch-free pipeline: 16 rows in flight per group (8 current + 8
// prefetch). Out-of-range slots redirect to the ZERO pad row (zrow) so the
// unrolled body needs no per-slot predication — adding zeros is free.
template <int R, int R1, int S1STR, int S2STR>
__device__ __forceinline__ void gmeanG(int b, int e, const int* __restrict__ csr,
                                       int zrow, const uint4* __restrict__ src1,
                                       const uint4* __restrict__ src2,
                                       uint4* __restrict__ dst, int c) {
  const uint_t SEL_LO = 0x00003F80u, SEL_HI = 0x3F800000u;
  int n = e - b;
  const uint4* sp; int sstr; int cc;
  if (c < R1) { sp = src1; sstr = S1STR; cc = c; }
  else if (c < R) { sp = src2; sstr = S2STR; cc = c - R1; }
  else { sp = src1; sstr = S1STR; cc = 0; }  // dummy lanes: harmless in-line load
  float acc[8];
#pragma unroll
  for (int k = 0; k < 8; ++k) acc[k] = 0.f;
  uint4 vv[8];
#pragma unroll
  for (int k = 0; k < 8; ++k) {
    int j = (k < n) ? csr[b + k] : zrow;
    vv[k] = sp[(size_t)j * sstr + cc];
  }
  for (int it = 8; it < n; it += 8) {
    uint4 pv[8];
#pragma unroll
    for (int k = 0; k < 8; ++k) {
      int j = (it + k < n) ? csr[b + it + k] : zrow;
      pv[k] = sp[(size_t)j * sstr + cc];
    }
#pragma unroll
    for (int k = 0; k < 8; ++k) { DACC8(vv[k]); }
#pragma unroll
    for (int k = 0; k < 8; ++k) vv[k] = pv[k];
  }
#pragma unroll
  for (int k = 0; k < 8; ++k) { DACC8(vv[k]); }
  if (c < R) {
    float inv = 1.0f / fmaxf((float)n, 1.0f);
    uint4 o;
    o.x = (uint_t)f2bf(acc[0] * inv) | ((uint_t)f2bf(acc[1] * inv) << 16);
    o.y = (uint_t)f2bf(acc[2] * inv) | ((uint_t)f2bf(acc[3] * inv) << 16);
    o.z = (uint_t)f2bf(acc[4] * inv) | ((uint_t)f2bf(acc[5] * inv) << 16);
    o.w = (uint_t)f2bf(acc[6] * inv) | ((uint_t)f2bf(acc[7] * inv) << 16);
    dst[c] = o;
  }
}

// layer 1. Users: 8-lane groups (64-d xs16 rows). Sellers: 16-lane groups,
// lanes 0-7 xu16 row (128 B), lanes 8-9 oh12 one-hot row (32 B) -> 80-d agg.
__global__ void gather1_k(const int* __restrict__ rpU, const int* __restrict__ csrU,
                          const ushort_t* __restrict__ xs16,
                          const int* __restrict__ rpS, const int* __restrict__ csrS,
                          const ushort_t* __restrict__ xu16,
                          const ushort_t* __restrict__ oh12,
                          ushort_t* __restrict__ aggU, ushort_t* __restrict__ aggS) {
  int wid = (blockIdx.x * 256 + threadIdx.x) >> 6;
  int lane = threadIdx.x & 63;
  if (wid < 25000) {
    int g = lane >> 3, c = lane & 7;
    int u = wid * 8 + g;
    gmeanG<8, 8, 8, 8>(rpU[u], rpU[u + 1], csrU, NS_N, (const uint4*)xs16,
                       (const uint4*)xs16, (uint4*)(aggU + (size_t)u * 64), c);
  } else {
    int w2 = wid - 25000;  // [0,12500)
    int g = lane >> 4, c = lane & 15;
    int s = w2 * 4 + g;
    gmeanG<10, 8, 8, 2>(rpS[s], rpS[s + 1], csrS, NU_N, (const uint4*)xu16,
                        (const uint4*)oh12, (uint4*)(aggS + (size_t)s * 80), c);
  }
}

// layer 2: 16-lane groups (128-d rows, 256 B), 4 nodes/wave.
__global__ void gather2_k(const int* __restrict__ rpU, const int* __restrict__ csrU,
                          const ushort_t* __restrict__ s1,
                          const int* __restrict__ rpS, const int* __restrict__ csrS,
                          const ushort_t* __restrict__ u1,
                          ushort_t* __restrict__ aggU, ushort_t* __restrict__ aggS) {
  int wid = (blockIdx.x * 256 + threadIdx.x) >> 6;
  int lane = threadIdx.x & 63;
  int g = lane >> 4, c = lane & 15;
  if (wid < 50000) {
    int u = wid * 4 + g;
    gmeanG<16, 16, 16, 16>(rpU[u], rpU[u + 1], csrU, NS_N, (const uint4*)s1,
                           (const uint4*)s1, (uint4*)(aggU + (size_t)u * 128), c);
  } else {
    int w2 = wid - 50000;  // [0,12500)
    int s = w2 * 4 + g;
    gmeanG<16, 16, 16, 16>(rpS[s], rpS[s + 1], csrS, NU_N, (const uint4*)u1,
                           (const uint4*)u1, (uint4*)(aggS + (size_t)s * 128), c);
  }
}

// ===================== MFMA row-GEMM core (bf16 in, bf16 out) =====================
template <int KM, int KS, int SSTR, bool TBL>
__device__ __forceinline__ void gemm_core(
    short* sW, int bid, int nrows, const ushort_t* __restrict__ agg,
    const ushort_t* self, const ushort_t* __restrict__ wswz,
    const float* __restrict__ bias, const float* __restrict__ tbl27,
    const int* __restrict__ x1, ushort_t* out) {
  constexpr int K = KM + KS;
  constexpr int NKT = K / 16;
  {
    const uint4* g4 = (const uint4*)wswz;
    uint4* s4 = (uint4*)sW;
    for (int i = threadIdx.x; i < K * 16; i += 256) s4[i] = g4[i];
  }
  __syncthreads();

  int wave = threadIdx.x >> 6, lane = threadIdx.x & 63;
  int r0 = bid * 256 + wave * 64;
  int qk = (lane >> 5) << 3;

  int ra = r0 + (lane & 31), rb = ra + 32;
  int rac = (ra < nrows) ? ra : 0, rbc = (rb < nrows) ? rb : 0;

  f32x16 acc[2][4];
#pragma unroll
  for (int rt = 0; rt < 2; ++rt)
#pragma unroll
    for (int ct = 0; ct < 4; ++ct) acc[rt][ct] = (f32x16)0.0f;

  const short8* sWv = (const short8*)sW;

#pragma unroll
  for (int kt = 0; kt < NKT; ++kt) {
    int k0 = kt * 16 + qk;
    short8 af, bf;
    if (kt * 16 < KM) {
      af = *((const short8*)(agg + (size_t)rac * KM + k0));
      bf = *((const short8*)(agg + (size_t)rbc * KM + k0));
    } else {
      af = *((const short8*)(self + (size_t)rac * SSTR + (k0 - KM)));
      bf = *((const short8*)(self + (size_t)rbc * SSTR + (k0 - KM)));
    }
#pragma unroll
    for (int ct = 0; ct < 4; ++ct) {
      short8 wf = sWv[(ct * NKT + kt) * 64 + lane];
      acc[0][ct] = __builtin_amdgcn_mfma_f32_32x32x16_bf16(af, wf, acc[0][ct], 0, 0, 0);
      acc[1][ct] = __builtin_amdgcn_mfma_f32_32x32x16_bf16(bf, wf, acc[1][ct], 0, 0, 0);
    }
  }

  int nloc = lane & 31;
  float bn[4];
#pragma unroll
  for (int ct = 0; ct < 4; ++ct) bn[ct] = bias[ct * 32 + nloc];
  int rowq = 4 * (lane >> 5);
#pragma unroll
  for (int rt = 0; rt < 2; ++rt) {
#pragma unroll
    for (int reg = 0; reg < 16; ++reg) {
      int row = r0 + rt * 32 + (reg & 3) + 8 * (reg >> 2) + rowq;
      if (row < nrows) {
        const float* tp = nullptr;
        if (TBL) {
          int a = x1[2 * row], g = x1[2 * row + 1];
          tp = tbl27 + (a * 3 + g) * 128 + nloc;
        }
#pragma unroll
        for (int ct = 0; ct < 4; ++ct) {
          float v = acc[rt][ct][reg] + bn[ct];
          if (TBL) v += tp[ct * 32];
          out[(size_t)row * 128 + ct * 32 + nloc] = f2bf(fmaxf(v, 0.0f));
        }
      }
    }
  }
}

// merged layer-1 GEMM: blocks [0,NUBG) user (K=128), [NUBG,+NSBG) seller (K=144)
__global__ __launch_bounds__(256, 2) void gemm1_k(
    const ushort_t* __restrict__ aggU, const ushort_t* __restrict__ aggS,
    const ushort_t* __restrict__ xu16, const ushort_t* __restrict__ xs16,
    const ushort_t* __restrict__ z1u, const ushort_t* __restrict__ z1s,
    const float* __restrict__ b1u, const float* __restrict__ b1s,
    const float* __restrict__ tbl27, const int* __restrict__ x1,
    ushort_t* __restrict__ ub, ushort_t* __restrict__ sb) {
  extern __shared__ short smem[];
  if (blockIdx.x < NUBG)
    gemm_core<64, 64, 64, true>(smem, blockIdx.x, NU_N, aggU, xu16, z1u, b1u, tbl27, x1, ub);
  else
    gemm_core<80, 64, 64, false>(smem, blockIdx.x - NUBG, NS_N, aggS, xs16, z1s, b1s,
                                 nullptr, nullptr, sb);
}

// merged layer-2 GEMM (both K=256, in-place)
__global__ __launch_bounds__(256, 2) void gemm2_k(
    const ushort_t* __restrict__ aggU, const ushort_t* __restrict__ aggS,
    const ushort_t* __restrict__ z2u, const ushort_t* __restrict__ z2s,
    const float* __restrict__ b2u, const float* __restrict__ b2s,
    ushort_t* ub, ushort_t* sb) {
  extern __shared__ short smem[];
  if (blockIdx.x < NUBG)
    gemm_core<128, 128, 128, false>(smem, blockIdx.x, NU_N, aggU, ub, z2u, b2u,
                                    nullptr, nullptr, ub);
  else
    gemm_core<128, 128, 128, false>(smem, blockIdx.x - NUBG, NS_N, aggS, sb, z2s, b2s,
                                    nullptr, nullptr, sb);
}

// ===================== final =====================
__global__ void final_k(const ushort_t* __restrict__ u2, const ushort_t* __restrict__ s2,
                        const int* __restrict__ mu, const int* __restrict__ ms,
                        const float* __restrict__ lw, const float* __restrict__ lb,
                        float* __restrict__ out) {
  int w = (blockIdx.x * blockDim.x + threadIdx.x) >> 6;
  int lane = threadIdx.x & 63;
  if (w >= M_N) return;
  int iu = mu[w], is = ms[w];
  uint_t a = ((const uint_t*)(u2 + (size_t)iu * 128))[lane];
  uint_t b = ((const uint_t*)(s2 + (size_t)is * 128))[lane];
  float p = bf2f(a & 0xffffu) * lw[2 * lane] + bf2f(a >> 16) * lw[2 * lane + 1]
          + bf2f(b & 0xffffu) * lw[128 + 2 * lane] + bf2f(b >> 16) * lw[129 + 2 * lane];
#pragma unroll
  for (int off = 32; off > 0; off >>= 1) p += __shfl_down(p, off, 64);
  if (lane == 0) out[w] = 1.0f / (1.0f + expf(-(p + lb[0])));
}

extern "C" void kernel_launch(void* const* d_in, const int* in_sizes, int n_in,
                              void* d_out, int out_size, void* d_ws, size_t ws_size,
                              hipStream_t stream) {
  const float* xu   = (const float*)d_in[0];
  const float* xs   = (const float*)d_in[1];
  const int*   x1   = (const int*)d_in[2];
  const int*   su   = (const int*)d_in[3];
  const int*   ds   = (const int*)d_in[4];
  const int*   ss   = (const int*)d_in[5];
  const int*   du   = (const int*)d_in[6];
  const int*   mu   = (const int*)d_in[7];
  const int*   ms   = (const int*)d_in[8];
  const float* age  = (const float*)d_in[9];
  const float* gen  = (const float*)d_in[10];
  const float* W1ul = (const float*)d_in[11];
  const float* W1ur = (const float*)d_in[12];
  const float* b1u  = (const float*)d_in[13];
  const float* W1sl = (const float*)d_in[14];
  const float* W1sr = (const float*)d_in[15];
  const float* b1s  = (const float*)d_in[16];
  const float* W2ul = (const float*)d_in[17];
  const float* W2ur = (const float*)d_in[18];
  const float* b2u  = (const float*)d_in[19];
  const float* W2sl = (const float*)d_in[20];
  const float* W2sr = (const float*)d_in[21];
  const float* b2s  = (const float*)d_in[22];
  const float* lw   = (const float*)d_in[23];
  const float* lb   = (const float*)d_in[24];

  char* w = (char*)d_ws;
  ushort_t* aggU = (ushort_t*)(w + OFF_AGGU);
  ushort_t* aggS = (ushort_t*)(w + OFF_AGGS);
  ushort_t* ub   = (ushort_t*)(w + OFF_U);
  ushort_t* sb   = (ushort_t*)(w + OFF_S);
  ushort_t* xu16 = (ushort_t*)(w + OFF_XU16);
  ushort_t* xs16 = (ushort_t*)(w + OFF_XS16);
  float* tbl27   = (float*)(w + OFF_TBL27);
  ushort_t* z1u  = (ushort_t*)(w + OFF_Z1U);
  ushort_t* z1s  = (ushort_t*)(w + OFF_Z1S);
  ushort_t* z2u  = (ushort_t*)(w + OFF_Z2U);
  ushort_t* z2s  = (ushort_t*)(w + OFF_Z2S);
  int* rpU    = (int*)(w + OFF_RPU);
  int* rpS    = (int*)(w + OFF_RPS);
  int* csrU   = (int*)(w + OFF_CSRU);
  int* csrS   = (int*)(w + OFF_CSRS);
  int2* tmpU  = (int2*)(w + OFF_TMPU);
  int2* tmpS  = (int2*)(w + OFF_TMPS);
  int* cmatU  = (int*)(w + OFF_CMU);
  int* cmatS  = (int*)(w + OFF_CMS);
  int* cmatUs = (int*)(w + OFF_CMUS);
  int* cmatSs = (int*)(w + OFF_CMSS);
  ushort_t* oh12 = (ushort_t*)(w + OFF_U);  // aliases ub pre-gemm1
  int* part   = (int*)(w + OFF_PART);
  float* out = (float*)d_out;

  // ---- CSR build: 2-level LDS counting sort, zero global atomics ----
  hist_lds_k<<<2 * NCH, 256, 0, stream>>>(du, ds, cmatU, cmatS);
  scan1_k<<<2 * NCB, 256, 0, stream>>>(cmatU, cmatS, cmatUs, cmatSs, part);
  scan2_k<<<2, 1024, 0, stream>>>(part);
  scan3_k<<<2 * NCB, 256, 0, stream>>>(cmatUs, cmatSs, part);
  scatter_k<<<2 * NCH, 256, 0, stream>>>(du, ds, su, ss, cmatUs, cmatSs, tmpU, tmpS);
  build_k<<<2 * NBKT, 256, 0, stream>>>(cmatUs, cmatSs, tmpU, tmpS,
                                        rpU, rpS, csrU, csrS);
  prep_all_k<<<16813, 256, 0, stream>>>(xu, xs, x1, age, gen,
                                        W1ul, W1ur, W1sl, W1sr, W2ul, W2ur, W2sl, W2sr,
                                        xu16, xs16, ub, sb, oh12, tbl27,
                                        z1u, z1s, z2u, z2s);

  // ---- layer 1: 37500 waves (25000 user x8 + 12500 seller x4) ----
  gather1_k<<<9375, 256, 0, stream>>>(rpU, csrU, xs16, rpS, csrS, xu16, oh12,
                                      aggU, aggS);
  gemm1_k<<<NUBG + NSBG, 256, 144 * 128 * 2, stream>>>(aggU, aggS, xu16, xs16, z1u, z1s,
                                                       b1u, b1s, tbl27, x1, ub, sb);

  // ---- layer 2: 62500 waves (50000 user x4 + 12500 seller x4) ----
  gather2_k<<<15625, 256, 0, stream>>>(rpU, csrU, sb, rpS, csrS, ub, aggU, aggS);
  gemm2_k<<<NUBG + NSBG, 256, 256 * 128 * 2, stream>>>(aggU, aggS, z2u, z2s,
                                                       b2u, b2s, ub, sb);

  // ---- final linear + sigmoid ----
  final_k<<<(M_N * 64 + 255) / 256, 256, 0, stream>>>(ub, sb, mu, ms, lw, lb, out);
}

// Round 6
// 443.916 us; speedup vs baseline: 1.1061x; 1.1061x over previous
//
#include <hip/hip_runtime.h>
#include <math.h>

#define NU_N 200000
#define NS_N 50000
#define E_N  1000000
#define M_N  100000
#define NUBG 782   // ceil(NU/256) gemm blocks
#define NSBG 196   // ceil(NS/256)

// ---- CSR build (2-level LDS counting sort) geometry ----
#define CH_E 2048      // edges per chunk
#define NCH  489       // ceil(E/CH_E)
#define NBKT 391       // coarse buckets per side (users: node>>9, sellers: node>>7)
#define CM   191199    // NBKT*NCH cmat entries per side
#define NCB  747       // ceil(CM/256) scan blocks per side
#define PREPB 16813    // prep blocks (ceil(4303908/256))

typedef __attribute__((ext_vector_type(8))) short short8;
typedef __attribute__((ext_vector_type(16))) float f32x16;
typedef unsigned short ushort_t;
typedef unsigned int uint_t;

// ---- workspace layout (bytes), ~174 MB ----
static constexpr size_t OFF_AGGU  = 0;             // NU x 128 bf16 (L1: stride 64, L2: 128)
                                                   // [ hosts tmpU|tmpS pair arrays (16 MB) pre-gather1 ]
static constexpr size_t OFF_AGGS  = 51200000;      // NS x 128 bf16 (L1: stride 80, L2: 128)
                                                   // [ hosts cmat arrays (3.1 MB) pre-gather1 ]
static constexpr size_t OFF_U     = 64000000;      // (NU+1) x 128 bf16 (+zero pad row)
                                                   // [ first 6.4 MB hosts oh12 pre-gemm1 ]
static constexpr size_t OFF_S     = 115200256;     // (NS+1) x 128 bf16
static constexpr size_t OFF_XU16  = 128000512;     // (NU+1) x 64 bf16
static constexpr size_t OFF_XS16  = 153600640;     // (NS+1) x 64 bf16
static constexpr size_t OFF_TBL27 = 160000768;     // 27 x 128 f32
static constexpr size_t OFF_Z1U   = 160014592;     // K=128 swizzled bf16
static constexpr size_t OFF_Z1S   = 160047360;     // K=144 (64 xu | 9 age | 3 gen | 4 pad | 64 self)
static constexpr size_t OFF_Z2U   = 160084224;     // K=256
static constexpr size_t OFF_Z2S   = 160149760;     // K=256
static constexpr size_t OFF_RPU   = 160215296;     // (NU+1) int
static constexpr size_t OFF_RPS   = 161015312;     // (NS+1) int
static constexpr size_t OFF_CSRU  = 161215328;     // (E+8) int
static constexpr size_t OFF_CSRS  = 165215360;     // (E+8) int
static constexpr size_t OFF_PART  = 173615392;     // 2 x 1024 int

// cmat/tmp aliases
static constexpr size_t OFF_TMPU = OFF_AGGU;                 // E x int2
static constexpr size_t OFF_TMPS = OFF_AGGU + 8000000;       // E x int2
static constexpr size_t OFF_CMU  = OFF_AGGS;                 // CM ints
static constexpr size_t OFF_CMS  = OFF_AGGS + 764800;
static constexpr size_t OFF_CMUS = OFF_AGGS + 1529600;
static constexpr size_t OFF_CMSS = OFF_AGGS + 2294400;

__device__ inline ushort_t f2bf(float f) {
  union { float f; uint_t u; } c; c.f = f;
  uint_t r = (c.u + 0x7FFFu + ((c.u >> 16) & 1u)) >> 16;
  return (ushort_t)r;
}
__device__ inline float u2f(uint_t u) {
  union { uint_t u; float f; } c; c.u = u;
  return c.f;
}
__device__ inline float bf2f(uint_t u) { return u2f(u << 16); }

// ===================== merged prep + hist (independent work, one dispatch) =======
// blocks [0,978): per-chunk LDS histogram over NBKT coarse buckets -> cmat[b][c].
// blocks [978,978+PREPB): bf16 feats + pads + tbl27 + oh12 + weight swizzles.
__global__ void prep_hist_k(const float* __restrict__ xu, const float* __restrict__ xs,
                            const int* __restrict__ x1, const float* __restrict__ age,
                            const float* __restrict__ gen,
                            const float* __restrict__ W1ul, const float* __restrict__ W1ur,
                            const float* __restrict__ W1sl, const float* __restrict__ W1sr,
                            const float* __restrict__ W2ul, const float* __restrict__ W2ur,
                            const float* __restrict__ W2sl, const float* __restrict__ W2sr,
                            ushort_t* __restrict__ xu16, ushort_t* __restrict__ xs16,
                            ushort_t* __restrict__ ub, ushort_t* __restrict__ sb,
                            ushort_t* __restrict__ oh12,
                            float* __restrict__ tbl27,
                            ushort_t* __restrict__ z1u, ushort_t* __restrict__ z1s,
                            ushort_t* __restrict__ z2u, ushort_t* __restrict__ z2s,
                            const int* __restrict__ du, const int* __restrict__ ds,
                            int* __restrict__ cmatU, int* __restrict__ cmatS) {
  __shared__ int h[NBKT];
  if (blockIdx.x < 2 * NCH) {  // ---- hist path ----
    int bid = blockIdx.x;
    int side = bid >= NCH;
    int c = side ? bid - NCH : bid;
    const int* nd = side ? ds : du;
    int shift = side ? 7 : 9;
    int* cm = side ? cmatS : cmatU;
    for (int i = threadIdx.x; i < NBKT; i += 256) h[i] = 0;
    __syncthreads();
    int e0 = c * CH_E, e1 = min(E_N, e0 + CH_E);
    for (int e = e0 + (int)threadIdx.x; e < e1; e += 256)
      atomicAdd(&h[nd[e] >> shift], 1);
    __syncthreads();
    for (int b = threadIdx.x; b < NBKT; b += 256) cm[b * NCH + c] = h[b];
    return;
  }
  // ---- prep path ----
  int t = (blockIdx.x - 2 * NCH) * 256 + threadIdx.x;
  if (t < 4000000) {  // xu16 (3.2M float4s) then xs16 (800k)
    const float* src = (t < 3200000) ? xu : xs;
    ushort_t* dst = (t < 3200000) ? xu16 : xs16;
    int i = (t < 3200000) ? t : t - 3200000;
    float4 v = ((const float4*)src)[i];
    uint2 o;
    o.x = (uint_t)f2bf(v.x) | ((uint_t)f2bf(v.y) << 16);
    o.y = (uint_t)f2bf(v.z) | ((uint_t)f2bf(v.w) << 16);
    ((uint2*)dst)[i] = o;
  } else if (t < 4000100) {  // zero pad rows (incl. oh12 pad row)
    int t3 = t - 4000000;
    uint2 z; z.x = 0u; z.y = 0u;
    if (t3 < 16)       ((uint2*)xu16)[NU_N * 16 + t3] = z;
    else if (t3 < 32)  ((uint2*)xs16)[NS_N * 16 + (t3 - 16)] = z;
    else if (t3 < 64)  ((uint2*)ub)[NU_N * 32 + (t3 - 32)] = z;
    else if (t3 < 96)  ((uint2*)sb)[NS_N * 32 + (t3 - 64)] = z;
    else               ((uint2*)oh12)[NU_N * 4 + (t3 - 96)] = z;
  } else if (t < 4003556) {  // tbl27: 27 x 128
    int i = t - 4000100;
    int tt = i >> 7, j = i & 127;
    int a = tt / 3, g = tt % 3;
    float acc = 0.f;
    for (int k = 0; k < 32; ++k) acc += age[a * 32 + k] * W1ur[k * 128 + j];
    for (int k = 0; k < 32; ++k) acc += gen[g * 32 + k] * W1ur[(32 + k) * 128 + j];
    tbl27[i] = acc;
  } else if (t < 4019940) {  // z1u: K=128 (W1ul 64 | W1ur[64:128])
    int i = t - 4003556;
    int j = i & 7, lane = (i >> 3) & 63, rest = i >> 9;
    int kt = rest % 8, ct = rest / 8;
    int k = kt * 16 + ((lane >> 5) << 3) + j;
    int n = ct * 32 + (lane & 31);
    float v = (k < 64) ? W1ul[k * 128 + n] : W1ur[k * 128 + n];
    z1u[i] = f2bf(v);
  } else if (t < 4038372) {  // z1s: K=144 (W1sl[64:128] | ageW 9 | genW 3 | 0 x4 | W1sr 64)
    int i = t - 4019940;
    int j = i & 7, lane = (i >> 3) & 63, rest = i >> 9;
    int kt = rest % 9, ct = rest / 9;
    int k = kt * 16 + ((lane >> 5) << 3) + j;
    int n = ct * 32 + (lane & 31);
    float v;
    if (k < 64) v = W1sl[(64 + k) * 128 + n];
    else if (k < 73) {
      int a = k - 64; v = 0.f;
      for (int kk = 0; kk < 32; ++kk) v += age[a * 32 + kk] * W1sl[kk * 128 + n];
    } else if (k < 76) {
      int g = k - 73; v = 0.f;
      for (int kk = 0; kk < 32; ++kk) v += gen[g * 32 + kk] * W1sl[(32 + kk) * 128 + n];
    } else if (k < 80) v = 0.f;
    else v = W1sr[(k - 80) * 128 + n];
    z1s[i] = f2bf(v);
  } else if (t < 4103908) {  // z2u then z2s: K=256
    int i = t - 4038372;
    const float *Wl, *Wr; ushort_t* dst;
    if (i < 32768) { Wl = W2ul; Wr = W2ur; dst = z2u; }
    else { Wl = W2sl; Wr = W2sr; dst = z2s; i -= 32768; }
    int j = i & 7, lane = (i >> 3) & 63, rest = i >> 9;
    int kt = rest % 16, ct = rest / 16;
    int k = kt * 16 + ((lane >> 5) << 3) + j;
    int n = ct * 32 + (lane & 31);
    float v = (k < 128) ? Wl[k * 128 + n] : Wr[(k - 128) * 128 + n];
    dst[i] = f2bf(v);
  } else if (t < 4303908) {  // oh12: NU x 16 bf16 one-hot(age)|one-hot(gen)|4 zeros
    int r = t - 4103908;
    int2 ag = ((const int2*)x1)[r];
    uint_t wds[8];
#pragma unroll
    for (int ww = 0; ww < 8; ++ww) {
      int d0 = 2 * ww, d1 = 2 * ww + 1;
      uint_t lo = ((d0 == ag.x) || (d0 == 9 + ag.y)) ? 0x3F80u : 0u;
      uint_t hi = ((d1 == ag.x) || (d1 == 9 + ag.y)) ? 0x3F80u : 0u;
      wds[ww] = lo | (hi << 16);
    }
    uint4* orow = (uint4*)(oh12 + (size_t)r * 16);
    uint4 o0; o0.x = wds[0]; o0.y = wds[1]; o0.z = wds[2]; o0.w = wds[3];
    uint4 o1; o1.x = wds[4]; o1.y = wds[5]; o1.z = wds[6]; o1.w = wds[7];
    orow[0] = o0;
    orow[1] = o1;
  }
}

// ===================== scan (2 dispatches: partials, then offset+apply) =========
__global__ void scan1_k(const int* __restrict__ cmU, const int* __restrict__ cmS,
                        int* __restrict__ outU, int* __restrict__ outS,
                        int* __restrict__ part) {
  __shared__ int s[256];
  int blk = blockIdx.x;
  const int* in; int* out; int* pp;
  if (blk < NCB) { in = cmU; out = outU; pp = part; }
  else { blk -= NCB; in = cmS; out = outS; pp = part + 1024; }
  int t = threadIdx.x;
  int idx = blk * 256 + t;
  int v = (idx > 0 && idx <= CM) ? in[idx - 1] : 0;
  s[t] = v;
  __syncthreads();
  for (int off = 1; off < 256; off <<= 1) {
    int x = (t >= off) ? s[t - off] : 0;
    __syncthreads();
    s[t] += x;
    __syncthreads();
  }
  if (idx < CM) out[idx] = s[t];
  if (t == 255) pp[blk] = s[255];
}

// scan3 with inlined scan2: each block reduces its predecessor partials itself
// (<=747 strided loads + LDS tree), then adds the offset. Kills a dispatch.
__global__ void scan3_k(int* __restrict__ outU, int* __restrict__ outS,
                        const int* __restrict__ part) {
  __shared__ int red[256];
  int blk = blockIdx.x;
  int* out; const int* pp;
  if (blk < NCB) { out = outU; pp = part; }
  else { blk -= NCB; out = outS; pp = part + 1024; }
  int t = threadIdx.x;
  int s = 0;
  for (int i = t; i < blk; i += 256) s += pp[i];
  red[t] = s;
  __syncthreads();
  for (int off = 128; off > 0; off >>= 1) {
    if (t < off) red[t] += red[t + off];
    __syncthreads();
  }
  int off0 = red[0];
  int idx = blk * 256 + t;
  if (idx < CM) out[idx] += off0;
}

// Pass 2: per-chunk scatter to bucket-major tmp pairs (node, value).
__global__ void scatter_k(const int* __restrict__ du, const int* __restrict__ ds,
                          const int* __restrict__ su, const int* __restrict__ ss,
                          const int* __restrict__ cmUs, const int* __restrict__ cmSs,
                          int2* __restrict__ tmpU, int2* __restrict__ tmpS) {
  __shared__ int cur[NBKT];
  int side = blockIdx.x >= NCH;
  int c = side ? blockIdx.x - NCH : blockIdx.x;
  const int* nd = side ? ds : du;
  const int* vv = side ? su : ss;
  const int* cms = side ? cmSs : cmUs;
  int2* tmp = side ? tmpS : tmpU;
  int shift = side ? 7 : 9;
  for (int b = threadIdx.x; b < NBKT; b += 256) cur[b] = cms[b * NCH + c];
  __syncthreads();
  int e0 = c * CH_E, e1 = min(E_N, e0 + CH_E);
  for (int e = e0 + (int)threadIdx.x; e < e1; e += 256) {
    int node = nd[e];
    int pos = atomicAdd(&cur[node >> shift], 1);
    int2 p; p.x = node; p.y = vv[e];
    tmp[pos] = p;
  }
}

// Pass 3: one block per bucket: exact LDS hist + scan -> rowptr + final CSR.
__global__ void build_k(const int* __restrict__ cmUs, const int* __restrict__ cmSs,
                        const int2* __restrict__ tmpU, const int2* __restrict__ tmpS,
                        int* __restrict__ rpU, int* __restrict__ rpS,
                        int* __restrict__ csrU, int* __restrict__ csrS) {
  __shared__ int cnt[512];
  __shared__ int s2[256];
  __shared__ int base[512];
  int side = blockIdx.x >= NBKT;
  int b = side ? blockIdx.x - NBKT : blockIdx.x;
  const int* cms = side ? cmSs : cmUs;
  const int2* tmp = side ? tmpS : tmpU;
  int* rp = side ? rpS : rpU;
  int* csr = side ? csrS : csrU;
  int nper = side ? 128 : 512;
  int nn = side ? NS_N : NU_N;
  int t = threadIdx.x;
  int start = cms[b * NCH];
  int end = (b + 1 < NBKT) ? cms[(b + 1) * NCH] : E_N;
  cnt[t] = 0; cnt[t + 256] = 0;
  __syncthreads();
  int nbase = b * nper;
  for (int i = start + t; i < end; i += 256) atomicAdd(&cnt[tmp[i].x - nbase], 1);
  __syncthreads();
  int a0 = cnt[2 * t], a1 = cnt[2 * t + 1];
  s2[t] = a0 + a1;
  __syncthreads();
  int v = s2[t];
  for (int off = 1; off < 256; off <<= 1) {
    int x = (t >= off) ? s2[t - off] : 0;
    __syncthreads();
    s2[t] += x;
    __syncthreads();
  }
  int ex = s2[t] - v;
  base[2 * t] = start + ex;
  base[2 * t + 1] = start + ex + a0;
  __syncthreads();
  for (int i = t; i < nper; i += 256) {
    int node = nbase + i;
    if (node < nn) rp[node] = base[i];
  }
  if (b == NBKT - 1 && t == 0) rp[nn] = E_N;
  __syncthreads();  // rowptr reads of base[] complete before cursors mutate
  for (int i = start + t; i < end; i += 256) {
    int2 p = tmp[i];
    int pos = atomicAdd(&base[p.x - nbase], 1);
    csr[pos] = p.y;
  }
}

// ===================== group-per-node gather core (dot2 + depth-4 pipeline) =====
// v_dot2_f32_bf16: acc += u.lo*sel.lo + u.hi*sel.hi (bf16 widened to f32, exact
// for sel in {1.0, 0.0}). SEL_LO adds the low bf16; SEL_HI the high. One
// instruction replaces unpack(shl/and)+v_add_f32 — halves hot-loop VALU.
__device__ __forceinline__ void dot2acc(float& a, uint_t u, uint_t sel) {
  asm("v_dot2_f32_bf16 %0, %1, %2, %0" : "+v"(a) : "v"(u), "v"(sel));
}
#define DACC8(V)                                             \
  dot2acc(acc[0], V.x, SEL_LO); dot2acc(acc[1], V.x, SEL_HI);\
  dot2acc(acc[2], V.y, SEL_LO); dot2acc(acc[3], V.y, SEL_HI);\
  dot2acc(acc[4], V.z, SEL_LO); dot2acc(acc[5], V.z, SEL_HI);\
  dot2acc(acc[6], V.w, SEL_LO); dot2acc(acc[7], V.w, SEL_HI);

// One G-lane group owns one node; lane c owns uint4 #c of the output row.
// Depth-4 branch-free pipeline (depth-8 regressed: VGPR 28->44, occupancy
// 67->43% — r5 post-mortem). Out-of-range slots redirect to the ZERO pad row.
template <int R, int R1, int S1STR, int S2STR>
__device__ __forceinline__ void gmeanG(int b, int e, const int* __restrict__ csr,
                                       int zrow, const uint4* __restrict__ src1,
                                       const uint4* __restrict__ src2,
                                       uint4* __restrict__ dst, int c) {
  const uint_t SEL_LO = 0x00003F80u, SEL_HI = 0x3F800000u;
  int n = e - b;
  const uint4* sp; int sstr; int cc;
  if (c < R1) { sp = src1; sstr = S1STR; cc = c; }
  else if (c < R) { sp = src2; sstr = S2STR; cc = c - R1; }
  else { sp = src1; sstr = S1STR; cc = 0; }  // dummy lanes: harmless in-line load
  float acc[8];
#pragma unroll
  for (int k = 0; k < 8; ++k) acc[k] = 0.f;
  int j0 = (0 < n) ? csr[b + 0] : zrow;
  int j1 = (1 < n) ? csr[b + 1] : zrow;
  int j2 = (2 < n) ? csr[b + 2] : zrow;
  int j3 = (3 < n) ? csr[b + 3] : zrow;
  uint4 v0 = sp[(size_t)j0 * sstr + cc];
  uint4 v1 = sp[(size_t)j1 * sstr + cc];
  uint4 v2 = sp[(size_t)j2 * sstr + cc];
  uint4 v3 = sp[(size_t)j3 * sstr + cc];
  for (int it = 4; it < n; it += 4) {
    int k0 = csr[b + it];
    int k1 = (it + 1 < n) ? csr[b + it + 1] : zrow;
    int k2 = (it + 2 < n) ? csr[b + it + 2] : zrow;
    int k3 = (it + 3 < n) ? csr[b + it + 3] : zrow;
    uint4 p0 = sp[(size_t)k0 * sstr + cc];
    uint4 p1 = sp[(size_t)k1 * sstr + cc];
    uint4 p2 = sp[(size_t)k2 * sstr + cc];
    uint4 p3 = sp[(size_t)k3 * sstr + cc];
    DACC8(v0); DACC8(v1); DACC8(v2); DACC8(v3);
    v0 = p0; v1 = p1; v2 = p2; v3 = p3;
  }
  DACC8(v0); DACC8(v1); DACC8(v2); DACC8(v3);
  if (c < R) {
    float inv = 1.0f / fmaxf((float)n, 1.0f);
    uint4 o;
    o.x = (uint_t)f2bf(acc[0] * inv) | ((uint_t)f2bf(acc[1] * inv) << 16);
    o.y = (uint_t)f2bf(acc[2] * inv) | ((uint_t)f2bf(acc[3] * inv) << 16);
    o.z = (uint_t)f2bf(acc[4] * inv) | ((uint_t)f2bf(acc[5] * inv) << 16);
    o.w = (uint_t)f2bf(acc[6] * inv) | ((uint_t)f2bf(acc[7] * inv) << 16);
    dst[c] = o;
  }
}

// layer 1. Users: 8-lane groups (64-d xs16 rows). Sellers: 16-lane groups,
// lanes 0-7 xu16 row (128 B), lanes 8-9 oh12 one-hot row (32 B) -> 80-d agg.
__global__ void gather1_k(const int* __restrict__ rpU, const int* __restrict__ csrU,
                          const ushort_t* __restrict__ xs16,
                          const int* __restrict__ rpS, const int* __restrict__ csrS,
                          const ushort_t* __restrict__ xu16,
                          const ushort_t* __restrict__ oh12,
                          ushort_t* __restrict__ aggU, ushort_t* __restrict__ aggS) {
  int wid = (blockIdx.x * 256 + threadIdx.x) >> 6;
  int lane = threadIdx.x & 63;
  if (wid < 25000) {
    int g = lane >> 3, c = lane & 7;
    int u = wid * 8 + g;
    gmeanG<8, 8, 8, 8>(rpU[u], rpU[u + 1], csrU, NS_N, (const uint4*)xs16,
                       (const uint4*)xs16, (uint4*)(aggU + (size_t)u * 64), c);
  } else {
    int w2 = wid - 25000;  // [0,12500)
    int g = lane >> 4, c = lane & 15;
    int s = w2 * 4 + g;
    gmeanG<10, 8, 8, 2>(rpS[s], rpS[s + 1], csrS, NU_N, (const uint4*)xu16,
                        (const uint4*)oh12, (uint4*)(aggS + (size_t)s * 80), c);
  }
}

// layer 2: 16-lane groups (128-d rows, 256 B), 4 nodes/wave.
__global__ void gather2_k(const int* __restrict__ rpU, const int* __restrict__ csrU,
                          const ushort_t* __restrict__ s1,
                          const int* __restrict__ rpS, const int* __restrict__ csrS,
                          const ushort_t* __restrict__ u1,
                          ushort_t* __restrict__ aggU, ushort_t* __restrict__ aggS) {
  int wid = (blockIdx.x * 256 + threadIdx.x) >> 6;
  int lane = threadIdx.x & 63;
  int g = lane >> 4, c = lane & 15;
  if (wid < 50000) {
    int u = wid * 4 + g;
    gmeanG<16, 16, 16, 16>(rpU[u], rpU[u + 1], csrU, NS_N, (const uint4*)s1,
                           (const uint4*)s1, (uint4*)(aggU + (size_t)u * 128), c);
  } else {
    int w2 = wid - 50000;  // [0,12500)
    int s = w2 * 4 + g;
    gmeanG<16, 16, 16, 16>(rpS[s], rpS[s + 1], csrS, NU_N, (const uint4*)u1,
                           (const uint4*)u1, (uint4*)(aggS + (size_t)s * 128), c);
  }
}

// ===================== MFMA row-GEMM core (bf16 in, bf16 out) =====================
template <int KM, int KS, int SSTR, bool TBL>
__device__ __forceinline__ void gemm_core(
    short* sW, int bid, int nrows, const ushort_t* __restrict__ agg,
    const ushort_t* self, const ushort_t* __restrict__ wswz,
    const float* __restrict__ bias, const float* __restrict__ tbl27,
    const int* __restrict__ x1, ushort_t* out) {
  constexpr int K = KM + KS;
  constexpr int NKT = K / 16;
  {
    const uint4* g4 = (const uint4*)wswz;
    uint4* s4 = (uint4*)sW;
    for (int i = threadIdx.x; i < K * 16; i += 256) s4[i] = g4[i];
  }
  __syncthreads();

  int wave = threadIdx.x >> 6, lane = threadIdx.x & 63;
  int r0 = bid * 256 + wave * 64;
  int qk = (lane >> 5) << 3;

  int ra = r0 + (lane & 31), rb = ra + 32;
  int rac = (ra < nrows) ? ra : 0, rbc = (rb < nrows) ? rb : 0;

  f32x16 acc[2][4];
#pragma unroll
  for (int rt = 0; rt < 2; ++rt)
#pragma unroll
    for (int ct = 0; ct < 4; ++ct) acc[rt][ct] = (f32x16)0.0f;

  const short8* sWv = (const short8*)sW;

#pragma unroll
  for (int kt = 0; kt < NKT; ++kt) {
    int k0 = kt * 16 + qk;
    short8 af, bf;
    if (kt * 16 < KM) {
      af = *((const short8*)(agg + (size_t)rac * KM + k0));
      bf = *((const short8*)(agg + (size_t)rbc * KM + k0));
    } else {
      af = *((const short8*)(self + (size_t)rac * SSTR + (k0 - KM)));
      bf = *((const short8*)(self + (size_t)rbc * SSTR + (k0 - KM)));
    }
#pragma unroll
    for (int ct = 0; ct < 4; ++ct) {
      short8 wf = sWv[(ct * NKT + kt) * 64 + lane];
      acc[0][ct] = __builtin_amdgcn_mfma_f32_32x32x16_bf16(af, wf, acc[0][ct], 0, 0, 0);
      acc[1][ct] = __builtin_amdgcn_mfma_f32_32x32x16_bf16(bf, wf, acc[1][ct], 0, 0, 0);
    }
  }

  int nloc = lane & 31;
  float bn[4];
#pragma unroll
  for (int ct = 0; ct < 4; ++ct) bn[ct] = bias[ct * 32 + nloc];
  int rowq = 4 * (lane >> 5);
#pragma unroll
  for (int rt = 0; rt < 2; ++rt) {
#pragma unroll
    for (int reg = 0; reg < 16; ++reg) {
      int row = r0 + rt * 32 + (reg & 3) + 8 * (reg >> 2) + rowq;
      if (row < nrows) {
        const float* tp = nullptr;
        if (TBL) {
          int a = x1[2 * row], g = x1[2 * row + 1];
          tp = tbl27 + (a * 3 + g) * 128 + nloc;
        }
#pragma unroll
        for (int ct = 0; ct < 4; ++ct) {
          float v = acc[rt][ct][reg] + bn[ct];
          if (TBL) v += tp[ct * 32];
          out[(size_t)row * 128 + ct * 32 + nloc] = f2bf(fmaxf(v, 0.0f));
        }
      }
    }
  }
}

// merged layer-1 GEMM: blocks [0,NUBG) user (K=128), [NUBG,+NSBG) seller (K=144)
__global__ __launch_bounds__(256, 2) void gemm1_k(
    const ushort_t* __restrict__ aggU, const ushort_t* __restrict__ aggS,
    const ushort_t* __restrict__ xu16, const ushort_t* __restrict__ xs16,
    const ushort_t* __restrict__ z1u, const ushort_t* __restrict__ z1s,
    const float* __restrict__ b1u, const float* __restrict__ b1s,
    const float* __restrict__ tbl27, const int* __restrict__ x1,
    ushort_t* __restrict__ ub, ushort_t* __restrict__ sb) {
  extern __shared__ short smem[];
  if (blockIdx.x < NUBG)
    gemm_core<64, 64, 64, true>(smem, blockIdx.x, NU_N, aggU, xu16, z1u, b1u, tbl27, x1, ub);
  else
    gemm_core<80, 64, 64, false>(smem, blockIdx.x - NUBG, NS_N, aggS, xs16, z1s, b1s,
                                 nullptr, nullptr, sb);
}

// merged layer-2 GEMM (both K=256, in-place)
__global__ __launch_bounds__(256, 2) void gemm2_k(
    const ushort_t* __restrict__ aggU, const ushort_t* __restrict__ aggS,
    const ushort_t* __restrict__ z2u, const ushort_t* __restrict__ z2s,
    const float* __restrict__ b2u, const float* __restrict__ b2s,
    ushort_t* ub, ushort_t* sb) {
  extern __shared__ short smem[];
  if (blockIdx.x < NUBG)
    gemm_core<128, 128, 128, false>(smem, blockIdx.x, NU_N, aggU, ub, z2u, b2u,
                                    nullptr, nullptr, ub);
  else
    gemm_core<128, 128, 128, false>(smem, blockIdx.x - NUBG, NS_N, aggS, sb, z2s, b2s,
                                    nullptr, nullptr, sb);
}

// ===================== final =====================
__global__ void final_k(const ushort_t* __restrict__ u2, const ushort_t* __restrict__ s2,
                        const int* __restrict__ mu, const int* __restrict__ ms,
                        const float* __restrict__ lw, const float* __restrict__ lb,
                        float* __restrict__ out) {
  int w = (blockIdx.x * blockDim.x + threadIdx.x) >> 6;
  int lane = threadIdx.x & 63;
  if (w >= M_N) return;
  int iu = mu[w], is = ms[w];
  uint_t a = ((const uint_t*)(u2 + (size_t)iu * 128))[lane];
  uint_t b = ((const uint_t*)(s2 + (size_t)is * 128))[lane];
  float p = bf2f(a & 0xffffu) * lw[2 * lane] + bf2f(a >> 16) * lw[2 * lane + 1]
          + bf2f(b & 0xffffu) * lw[128 + 2 * lane] + bf2f(b >> 16) * lw[129 + 2 * lane];
#pragma unroll
  for (int off = 32; off > 0; off >>= 1) p += __shfl_down(p, off, 64);
  if (lane == 0) out[w] = 1.0f / (1.0f + expf(-(p + lb[0])));
}

extern "C" void kernel_launch(void* const* d_in, const int* in_sizes, int n_in,
                              void* d_out, int out_size, void* d_ws, size_t ws_size,
                              hipStream_t stream) {
  const float* xu   = (const float*)d_in[0];
  const float* xs   = (const float*)d_in[1];
  const int*   x1   = (const int*)d_in[2];
  const int*   su   = (const int*)d_in[3];
  const int*   ds   = (const int*)d_in[4];
  const int*   ss   = (const int*)d_in[5];
  const int*   du   = (const int*)d_in[6];
  const int*   mu   = (const int*)d_in[7];
  const int*   ms   = (const int*)d_in[8];
  const float* age  = (const float*)d_in[9];
  const float* gen  = (const float*)d_in[10];
  const float* W1ul = (const float*)d_in[11];
  const float* W1ur = (const float*)d_in[12];
  const float* b1u  = (const float*)d_in[13];
  const float* W1sl = (const float*)d_in[14];
  const float* W1sr = (const float*)d_in[15];
  const float* b1s  = (const float*)d_in[16];
  const float* W2ul = (const float*)d_in[17];
  const float* W2ur = (const float*)d_in[18];
  const float* b2u  = (const float*)d_in[19];
  const float* W2sl = (const float*)d_in[20];
  const float* W2sr = (const float*)d_in[21];
  const float* b2s  = (const float*)d_in[22];
  const float* lw   = (const float*)d_in[23];
  const float* lb   = (const float*)d_in[24];

  char* w = (char*)d_ws;
  ushort_t* aggU = (ushort_t*)(w + OFF_AGGU);
  ushort_t* aggS = (ushort_t*)(w + OFF_AGGS);
  ushort_t* ub   = (ushort_t*)(w + OFF_U);
  ushort_t* sb   = (ushort_t*)(w + OFF_S);
  ushort_t* xu16 = (ushort_t*)(w + OFF_XU16);
  ushort_t* xs16 = (ushort_t*)(w + OFF_XS16);
  float* tbl27   = (float*)(w + OFF_TBL27);
  ushort_t* z1u  = (ushort_t*)(w + OFF_Z1U);
  ushort_t* z1s  = (ushort_t*)(w + OFF_Z1S);
  ushort_t* z2u  = (ushort_t*)(w + OFF_Z2U);
  ushort_t* z2s  = (ushort_t*)(w + OFF_Z2S);
  int* rpU    = (int*)(w + OFF_RPU);
  int* rpS    = (int*)(w + OFF_RPS);
  int* csrU   = (int*)(w + OFF_CSRU);
  int* csrS   = (int*)(w + OFF_CSRS);
  int2* tmpU  = (int2*)(w + OFF_TMPU);
  int2* tmpS  = (int2*)(w + OFF_TMPS);
  int* cmatU  = (int*)(w + OFF_CMU);
  int* cmatS  = (int*)(w + OFF_CMS);
  int* cmatUs = (int*)(w + OFF_CMUS);
  int* cmatSs = (int*)(w + OFF_CMSS);
  ushort_t* oh12 = (ushort_t*)(w + OFF_U);  // aliases ub pre-gemm1
  int* part   = (int*)(w + OFF_PART);
  float* out = (float*)d_out;

  // ---- merged prep + CSR hist (independent work, 1 dispatch) ----
  prep_hist_k<<<2 * NCH + PREPB, 256, 0, stream>>>(
      xu, xs, x1, age, gen, W1ul, W1ur, W1sl, W1sr, W2ul, W2ur, W2sl, W2sr,
      xu16, xs16, ub, sb, oh12, tbl27, z1u, z1s, z2u, z2s,
      du, ds, cmatU, cmatS);

  // ---- CSR build: LDS counting sort, zero global atomics ----
  scan1_k<<<2 * NCB, 256, 0, stream>>>(cmatU, cmatS, cmatUs, cmatSs, part);
  scan3_k<<<2 * NCB, 256, 0, stream>>>(cmatUs, cmatSs, part);
  scatter_k<<<2 * NCH, 256, 0, stream>>>(du, ds, su, ss, cmatUs, cmatSs, tmpU, tmpS);
  build_k<<<2 * NBKT, 256, 0, stream>>>(cmatUs, cmatSs, tmpU, tmpS,
                                        rpU, rpS, csrU, csrS);

  // ---- layer 1: 37500 waves (25000 user x8 + 12500 seller x4) ----
  gather1_k<<<9375, 256, 0, stream>>>(rpU, csrU, xs16, rpS, csrS, xu16, oh12,
                                      aggU, aggS);
  gemm1_k<<<NUBG + NSBG, 256, 144 * 128 * 2, stream>>>(aggU, aggS, xu16, xs16, z1u, z1s,
                                                       b1u, b1s, tbl27, x1, ub, sb);

  // ---- layer 2: 62500 waves (50000 user x4 + 12500 seller x4) ----
  gather2_k<<<15625, 256, 0, stream>>>(rpU, csrU, sb, rpS, csrS, ub, aggU, aggS);
  gemm2_k<<<NUBG + NSBG, 256, 256 * 128 * 2, stream>>>(aggU, aggS, z2u, z2s,
                                                       b2u, b2s, ub, sb);

  // ---- final linear + sigmoid ----
  final_k<<<(M_N * 64 + 255) / 256, 256, 0, stream>>>(ub, sb, mu, ms, lw, lb, out);
}

// Round 8
// 442.123 us; speedup vs baseline: 1.1105x; 1.0041x over previous
//
#include <hip/hip_runtime.h>
#include <math.h>

#define NU_N 200000
#define NS_N 50000
#define E_N  1000000
#define M_N  100000
#define NUBG 782   // ceil(NU/256) gemm blocks
#define NSBG 196   // ceil(NS/256)

// ---- CSR build (2-level LDS counting sort) geometry ----
#define CH_E 2048      // edges per chunk
#define NCH  489       // ceil(E/CH_E)
#define NBKT 391       // coarse buckets per side (users: node>>9, sellers: node>>7)
#define CM   191199    // NBKT*NCH cmat entries per side
#define NCB  747       // ceil(CM/256) scan blocks per side
#define PREPB 16813    // prep blocks (ceil(4303908/256))

typedef __attribute__((ext_vector_type(8))) short short8;
typedef __attribute__((ext_vector_type(16))) float f32x16;
typedef unsigned short ushort_t;
typedef unsigned int uint_t;

// ---- workspace layout (bytes), ~174 MB ----
static constexpr size_t OFF_AGGU  = 0;             // NU x 128 bf16
static constexpr size_t OFF_AGGS  = 51200000;      // NS x 128 bf16
static constexpr size_t OFF_U     = 64000000;      // (NU+1) x 128 bf16 (+zero pad row)
static constexpr size_t OFF_S     = 115200256;     // (NS+1) x 128 bf16
static constexpr size_t OFF_XU16  = 128000512;     // (NU+1) x 64 bf16
static constexpr size_t OFF_XS16  = 153600640;     // (NS+1) x 64 bf16
static constexpr size_t OFF_TBL27 = 160000768;     // 27 x 128 f32
static constexpr size_t OFF_Z1U   = 160014592;     // K=128 swizzled bf16
static constexpr size_t OFF_Z1S   = 160047360;     // K=144
static constexpr size_t OFF_Z2U   = 160084224;     // K=256
static constexpr size_t OFF_Z2S   = 160149760;     // K=256
static constexpr size_t OFF_RPU   = 160215296;     // (NU+1) int
static constexpr size_t OFF_RPS   = 161015312;     // (NS+1) int
static constexpr size_t OFF_CSRU  = 161215328;     // (E+8) int
static constexpr size_t OFF_CSRS  = 165215360;     // (E+8) int
static constexpr size_t OFF_PART  = 173615392;     // 2 x 1024 int

// cmat/tmp aliases
static constexpr size_t OFF_TMPU = OFF_AGGU;                 // E x int2
static constexpr size_t OFF_TMPS = OFF_AGGU + 8000000;       // E x int2
static constexpr size_t OFF_CMU  = OFF_AGGS;                 // CM ints
static constexpr size_t OFF_CMS  = OFF_AGGS + 764800;
static constexpr size_t OFF_CMUS = OFF_AGGS + 1529600;
static constexpr size_t OFF_CMSS = OFF_AGGS + 2294400;

__device__ inline ushort_t f2bf(float f) {
  union { float f; uint_t u; } c; c.f = f;
  uint_t r = (c.u + 0x7FFFu + ((c.u >> 16) & 1u)) >> 16;
  return (ushort_t)r;
}
__device__ inline float u2f(uint_t u) {
  union { uint_t u; float f; } c; c.u = u;
  return c.f;
}
__device__ inline float bf2f(uint_t u) { return u2f(u << 16); }

// ===================== merged prep + hist (independent work, one dispatch) =======
__global__ void prep_hist_k(const float* __restrict__ xu, const float* __restrict__ xs,
                            const int* __restrict__ x1, const float* __restrict__ age,
                            const float* __restrict__ gen,
                            const float* __restrict__ W1ul, const float* __restrict__ W1ur,
                            const float* __restrict__ W1sl, const float* __restrict__ W1sr,
                            const float* __restrict__ W2ul, const float* __restrict__ W2ur,
                            const float* __restrict__ W2sl, const float* __restrict__ W2sr,
                            ushort_t* __restrict__ xu16, ushort_t* __restrict__ xs16,
                            ushort_t* __restrict__ ub, ushort_t* __restrict__ sb,
                            ushort_t* __restrict__ oh12,
                            float* __restrict__ tbl27,
                            ushort_t* __restrict__ z1u, ushort_t* __restrict__ z1s,
                            ushort_t* __restrict__ z2u, ushort_t* __restrict__ z2s,
                            const int* __restrict__ du, const int* __restrict__ ds,
                            int* __restrict__ cmatU, int* __restrict__ cmatS) {
  __shared__ int h[NBKT];
  if (blockIdx.x < 2 * NCH) {  // ---- hist path ----
    int bid = blockIdx.x;
    int side = bid >= NCH;
    int c = side ? bid - NCH : bid;
    const int* nd = side ? ds : du;
    int shift = side ? 7 : 9;
    int* cm = side ? cmatS : cmatU;
    for (int i = threadIdx.x; i < NBKT; i += 256) h[i] = 0;
    __syncthreads();
    int e0 = c * CH_E, e1 = min(E_N, e0 + CH_E);
    for (int e = e0 + (int)threadIdx.x; e < e1; e += 256)
      atomicAdd(&h[nd[e] >> shift], 1);
    __syncthreads();
    for (int b = threadIdx.x; b < NBKT; b += 256) cm[b * NCH + c] = h[b];
    return;
  }
  // ---- prep path ----
  int t = (blockIdx.x - 2 * NCH) * 256 + threadIdx.x;
  if (t < 4000000) {  // xu16 (3.2M float4s) then xs16 (800k)
    const float* src = (t < 3200000) ? xu : xs;
    ushort_t* dst = (t < 3200000) ? xu16 : xs16;
    int i = (t < 3200000) ? t : t - 3200000;
    float4 v = ((const float4*)src)[i];
    uint2 o;
    o.x = (uint_t)f2bf(v.x) | ((uint_t)f2bf(v.y) << 16);
    o.y = (uint_t)f2bf(v.z) | ((uint_t)f2bf(v.w) << 16);
    ((uint2*)dst)[i] = o;
  } else if (t < 4000100) {  // zero pad rows (incl. oh12 pad row)
    int t3 = t - 4000000;
    uint2 z; z.x = 0u; z.y = 0u;
    if (t3 < 16)       ((uint2*)xu16)[NU_N * 16 + t3] = z;
    else if (t3 < 32)  ((uint2*)xs16)[NS_N * 16 + (t3 - 16)] = z;
    else if (t3 < 64)  ((uint2*)ub)[NU_N * 32 + (t3 - 32)] = z;
    else if (t3 < 96)  ((uint2*)sb)[NS_N * 32 + (t3 - 64)] = z;
    else               ((uint2*)oh12)[NU_N * 4 + (t3 - 96)] = z;
  } else if (t < 4003556) {  // tbl27: 27 x 128
    int i = t - 4000100;
    int tt = i >> 7, j = i & 127;
    int a = tt / 3, g = tt % 3;
    float acc = 0.f;
    for (int k = 0; k < 32; ++k) acc += age[a * 32 + k] * W1ur[k * 128 + j];
    for (int k = 0; k < 32; ++k) acc += gen[g * 32 + k] * W1ur[(32 + k) * 128 + j];
    tbl27[i] = acc;
  } else if (t < 4019940) {  // z1u: K=128 (W1ul 64 | W1ur[64:128])
    int i = t - 4003556;
    int j = i & 7, lane = (i >> 3) & 63, rest = i >> 9;
    int kt = rest % 8, ct = rest / 8;
    int k = kt * 16 + ((lane >> 5) << 3) + j;
    int n = ct * 32 + (lane & 31);
    float v = (k < 64) ? W1ul[k * 128 + n] : W1ur[k * 128 + n];
    z1u[i] = f2bf(v);
  } else if (t < 4038372) {  // z1s: K=144 (W1sl[64:128] | ageW 9 | genW 3 | 0 x4 | W1sr 64)
    int i = t - 4019940;
    int j = i & 7, lane = (i >> 3) & 63, rest = i >> 9;
    int kt = rest % 9, ct = rest / 9;
    int k = kt * 16 + ((lane >> 5) << 3) + j;
    int n = ct * 32 + (lane & 31);
    float v;
    if (k < 64) v = W1sl[(64 + k) * 128 + n];
    else if (k < 73) {
      int a = k - 64; v = 0.f;
      for (int kk = 0; kk < 32; ++kk) v += age[a * 32 + kk] * W1sl[kk * 128 + n];
    } else if (k < 76) {
      int g = k - 73; v = 0.f;
      for (int kk = 0; kk < 32; ++kk) v += gen[g * 32 + kk] * W1sl[(32 + kk) * 128 + n];
    } else if (k < 80) v = 0.f;
    else v = W1sr[(k - 80) * 128 + n];
    z1s[i] = f2bf(v);
  } else if (t < 4103908) {  // z2u then z2s: K=256
    int i = t - 4038372;
    const float *Wl, *Wr; ushort_t* dst;
    if (i < 32768) { Wl = W2ul; Wr = W2ur; dst = z2u; }
    else { Wl = W2sl; Wr = W2sr; dst = z2s; i -= 32768; }
    int j = i & 7, lane = (i >> 3) & 63, rest = i >> 9;
    int kt = rest % 16, ct = rest / 16;
    int k = kt * 16 + ((lane >> 5) << 3) + j;
    int n = ct * 32 + (lane & 31);
    float v = (k < 128) ? Wl[k * 128 + n] : Wr[(k - 128) * 128 + n];
    dst[i] = f2bf(v);
  } else if (t < 4303908) {  // oh12: NU x 16 bf16 one-hot(age)|one-hot(gen)|4 zeros
    int r = t - 4103908;
    int2 ag = ((const int2*)x1)[r];
    uint_t wds[8];
#pragma unroll
    for (int ww = 0; ww < 8; ++ww) {
      int d0 = 2 * ww, d1 = 2 * ww + 1;
      uint_t lo = ((d0 == ag.x) || (d0 == 9 + ag.y)) ? 0x3F80u : 0u;
      uint_t hi = ((d1 == ag.x) || (d1 == 9 + ag.y)) ? 0x3F80u : 0u;
      wds[ww] = lo | (hi << 16);
    }
    uint4* orow = (uint4*)(oh12 + (size_t)r * 16);
    uint4 o0; o0.x = wds[0]; o0.y = wds[1]; o0.z = wds[2]; o0.w = wds[3];
    uint4 o1; o1.x = wds[4]; o1.y = wds[5]; o1.z = wds[6]; o1.w = wds[7];
    orow[0] = o0;
    orow[1] = o1;
  }
}

// ===================== scan (2 dispatches) =========
__global__ void scan1_k(const int* __restrict__ cmU, const int* __restrict__ cmS,
                        int* __restrict__ outU, int* __restrict__ outS,
                        int* __restrict__ part) {
  __shared__ int s[256];
  int blk = blockIdx.x;
  const int* in; int* out; int* pp;
  if (blk < NCB) { in = cmU; out = outU; pp = part; }
  else { blk -= NCB; in = cmS; out = outS; pp = part + 1024; }
  int t = threadIdx.x;
  int idx = blk * 256 + t;
  int v = (idx > 0 && idx <= CM) ? in[idx - 1] : 0;
  s[t] = v;
  __syncthreads();
  for (int off = 1; off < 256; off <<= 1) {
    int x = (t >= off) ? s[t - off] : 0;
    __syncthreads();
    s[t] += x;
    __syncthreads();
  }
  if (idx < CM) out[idx] = s[t];
  if (t == 255) pp[blk] = s[255];
}

// scan3 with inlined scan2: each block reduces its predecessor partials itself
// (<=747 strided loads + LDS tree), then adds the offset.
__global__ void scan3_k(int* __restrict__ outU, int* __restrict__ outS,
                        const int* __restrict__ part) {
  __shared__ int red[256];
  int blk = blockIdx.x;
  int* out; const int* pp;
  if (blk < NCB) { out = outU; pp = part; }
  else { blk -= NCB; out = outS; pp = part + 1024; }
  int t = threadIdx.x;
  int s = 0;
  for (int i = t; i < blk; i += 256) s += pp[i];
  red[t] = s;
  __syncthreads();
  for (int off = 128; off > 0; off >>= 1) {
    if (t < off) red[t] += red[t + off];
    __syncthreads();
  }
  int off0 = red[0];
  int idx = blk * 256 + t;
  if (idx < CM) out[idx] += off0;
}

// Pass 2: per-chunk scatter to bucket-major tmp pairs (node, value).
__global__ void scatter_k(const int* __restrict__ du, const int* __restrict__ ds,
                          const int* __restrict__ su, const int* __restrict__ ss,
                          const int* __restrict__ cmUs, const int* __restrict__ cmSs,
                          int2* __restrict__ tmpU, int2* __restrict__ tmpS) {
  __shared__ int cur[NBKT];
  int side = blockIdx.x >= NCH;
  int c = side ? blockIdx.x - NCH : blockIdx.x;
  const int* nd = side ? ds : du;
  const int* vv = side ? su : ss;
  const int* cms = side ? cmSs : cmUs;
  int2* tmp = side ? tmpS : tmpU;
  int shift = side ? 7 : 9;
  for (int b = threadIdx.x; b < NBKT; b += 256) cur[b] = cms[b * NCH + c];
  __syncthreads();
  int e0 = c * CH_E, e1 = min(E_N, e0 + CH_E);
  for (int e = e0 + (int)threadIdx.x; e < e1; e += 256) {
    int node = nd[e];
    int pos = atomicAdd(&cur[node >> shift], 1);
    int2 p; p.x = node; p.y = vv[e];
    tmp[pos] = p;
  }
}

// Pass 3: one block per bucket: exact LDS hist + scan -> rowptr + final CSR.
__global__ void build_k(const int* __restrict__ cmUs, const int* __restrict__ cmSs,
                        const int2* __restrict__ tmpU, const int2* __restrict__ tmpS,
                        int* __restrict__ rpU, int* __restrict__ rpS,
                        int* __restrict__ csrU, int* __restrict__ csrS) {
  __shared__ int cnt[512];
  __shared__ int s2[256];
  __shared__ int base[512];
  int side = blockIdx.x >= NBKT;
  int b = side ? blockIdx.x - NBKT : blockIdx.x;
  const int* cms = side ? cmSs : cmUs;
  const int2* tmp = side ? tmpS : tmpU;
  int* rp = side ? rpS : rpU;
  int* csr = side ? csrS : csrU;
  int nper = side ? 128 : 512;
  int nn = side ? NS_N : NU_N;
  int t = threadIdx.x;
  int start = cms[b * NCH];
  int end = (b + 1 < NBKT) ? cms[(b + 1) * NCH] : E_N;
  cnt[t] = 0; cnt[t + 256] = 0;
  __syncthreads();
  int nbase = b * nper;
  for (int i = start + t; i < end; i += 256) atomicAdd(&cnt[tmp[i].x - nbase], 1);
  __syncthreads();
  int a0 = cnt[2 * t], a1 = cnt[2 * t + 1];
  s2[t] = a0 + a1;
  __syncthreads();
  int v = s2[t];
  for (int off = 1; off < 256; off <<= 1) {
    int x = (t >= off) ? s2[t - off] : 0;
    __syncthreads();
    s2[t] += x;
    __syncthreads();
  }
  int ex = s2[t] - v;
  base[2 * t] = start + ex;
  base[2 * t + 1] = start + ex + a0;
  __syncthreads();
  for (int i = t; i < nper; i += 256) {
    int node = nbase + i;
    if (node < nn) rp[node] = base[i];
  }
  if (b == NBKT - 1 && t == 0) rp[nn] = E_N;
  __syncthreads();  // rowptr reads of base[] complete before cursors mutate
  for (int i = start + t; i < end; i += 256) {
    int2 p = tmp[i];
    int pos = atomicAdd(&base[p.x - nbase], 1);
    csr[pos] = p.y;
  }
}

// ===================== group-per-node gather core (dot2 + depth-4 pipeline) =====
// v_dot2_f32_bf16: acc += u.lo*sel.lo + u.hi*sel.hi (exact for sel in {1.0,0.0}).
__device__ __forceinline__ void dot2acc(float& a, uint_t u, uint_t sel) {
  asm("v_dot2_f32_bf16 %0, %1, %2, %0" : "+v"(a) : "v"(u), "v"(sel));
}
#define DACC8(V)                                             \
  dot2acc(acc[0], V.x, SEL_LO); dot2acc(acc[1], V.x, SEL_HI);\
  dot2acc(acc[2], V.y, SEL_LO); dot2acc(acc[3], V.y, SEL_HI);\
  dot2acc(acc[4], V.z, SEL_LO); dot2acc(acc[5], V.z, SEL_HI);\
  dot2acc(acc[6], V.w, SEL_LO); dot2acc(acc[7], V.w, SEL_HI);

// One G-lane group owns one node; lane c owns uint4 #c of the output row.
// Depth-4 branch-free pipeline (depth-8 regressed: VGPR 28->44, occupancy
// 67->43%; LDS-ring failed refcheck — r5/r7 post-mortems). Out-of-range slots
// redirect to the ZERO pad row.
template <int R, int R1, int S1STR, int S2STR>
__device__ __forceinline__ void gmeanG(int b, int e, const int* __restrict__ csr,
                                       int zrow, const uint4* __restrict__ src1,
                                       const uint4* __restrict__ src2,
                                       uint4* __restrict__ dst, int c) {
  const uint_t SEL_LO = 0x00003F80u, SEL_HI = 0x3F800000u;
  int n = e - b;
  const uint4* sp; int sstr; int cc;
  if (c < R1) { sp = src1; sstr = S1STR; cc = c; }
  else if (c < R) { sp = src2; sstr = S2STR; cc = c - R1; }
  else { sp = src1; sstr = S1STR; cc = 0; }
  float acc[8];
#pragma unroll
  for (int k = 0; k < 8; ++k) acc[k] = 0.f;
  int j0 = (0 < n) ? csr[b + 0] : zrow;
  int j1 = (1 < n) ? csr[b + 1] : zrow;
  int j2 = (2 < n) ? csr[b + 2] : zrow;
  int j3 = (3 < n) ? csr[b + 3] : zrow;
  uint4 v0 = sp[(size_t)j0 * sstr + cc];
  uint4 v1 = sp[(size_t)j1 * sstr + cc];
  uint4 v2 = sp[(size_t)j2 * sstr + cc];
  uint4 v3 = sp[(size_t)j3 * sstr + cc];
  for (int it = 4; it < n; it += 4) {
    int k0 = csr[b + it];
    int k1 = (it + 1 < n) ? csr[b + it + 1] : zrow;
    int k2 = (it + 2 < n) ? csr[b + it + 2] : zrow;
    int k3 = (it + 3 < n) ? csr[b + it + 3] : zrow;
    uint4 p0 = sp[(size_t)k0 * sstr + cc];
    uint4 p1 = sp[(size_t)k1 * sstr + cc];
    uint4 p2 = sp[(size_t)k2 * sstr + cc];
    uint4 p3 = sp[(size_t)k3 * sstr + cc];
    DACC8(v0); DACC8(v1); DACC8(v2); DACC8(v3);
    v0 = p0; v1 = p1; v2 = p2; v3 = p3;
  }
  DACC8(v0); DACC8(v1); DACC8(v2); DACC8(v3);
  if (c < R) {
    float inv = 1.0f / fmaxf((float)n, 1.0f);
    uint4 o;
    o.x = (uint_t)f2bf(acc[0] * inv) | ((uint_t)f2bf(acc[1] * inv) << 16);
    o.y = (uint_t)f2bf(acc[2] * inv) | ((uint_t)f2bf(acc[3] * inv) << 16);
    o.z = (uint_t)f2bf(acc[4] * inv) | ((uint_t)f2bf(acc[5] * inv) << 16);
    o.w = (uint_t)f2bf(acc[6] * inv) | ((uint_t)f2bf(acc[7] * inv) << 16);
    dst[c] = o;
  }
}

// layer 1. Users: 8-lane groups (64-d xs16 rows). Sellers: 16-lane groups,
// lanes 0-7 xu16 row (128 B), lanes 8-9 oh12 one-hot row (32 B) -> 80-d agg.
__global__ void gather1_k(const int* __restrict__ rpU, const int* __restrict__ csrU,
                          const ushort_t* __restrict__ xs16,
                          const int* __restrict__ rpS, const int* __restrict__ csrS,
                          const ushort_t* __restrict__ xu16,
                          const ushort_t* __restrict__ oh12,
                          ushort_t* __restrict__ aggU, ushort_t* __restrict__ aggS) {
  int wid = (blockIdx.x * 256 + threadIdx.x) >> 6;
  int lane = threadIdx.x & 63;
  if (wid < 25000) {
    int g = lane >> 3, c = lane & 7;
    int u = wid * 8 + g;
    gmeanG<8, 8, 8, 8>(rpU[u], rpU[u + 1], csrU, NS_N, (const uint4*)xs16,
                       (const uint4*)xs16, (uint4*)(aggU + (size_t)u * 64), c);
  } else {
    int w2 = wid - 25000;  // [0,12500)
    int g = lane >> 4, c = lane & 15;
    int s = w2 * 4 + g;
    gmeanG<10, 8, 8, 2>(rpS[s], rpS[s + 1], csrS, NU_N, (const uint4*)xu16,
                        (const uint4*)oh12, (uint4*)(aggS + (size_t)s * 80), c);
  }
}

// layer 2: 16-lane groups (128-d rows, 256 B), 4 nodes/wave.
__global__ void gather2_k(const int* __restrict__ rpU, const int* __restrict__ csrU,
                          const ushort_t* __restrict__ s1,
                          const int* __restrict__ rpS, const int* __restrict__ csrS,
                          const ushort_t* __restrict__ u1,
                          ushort_t* __restrict__ aggU, ushort_t* __restrict__ aggS) {
  int wid = (blockIdx.x * 256 + threadIdx.x) >> 6;
  int lane = threadIdx.x & 63;
  int g = lane >> 4, c = lane & 15;
  if (wid < 50000) {
    int u = wid * 4 + g;
    gmeanG<16, 16, 16, 16>(rpU[u], rpU[u + 1], csrU, NS_N, (const uint4*)s1,
                           (const uint4*)s1, (uint4*)(aggU + (size_t)u * 128), c);
  } else {
    int w2 = wid - 50000;  // [0,12500)
    int s = w2 * 4 + g;
    gmeanG<16, 16, 16, 16>(rpS[s], rpS[s + 1], csrS, NU_N, (const uint4*)u1,
                           (const uint4*)u1, (uint4*)(aggS + (size_t)s * 128), c);
  }
}

// ===================== MFMA row-GEMM core (bf16 in, bf16 out) =====================
template <int KM, int KS, int SSTR, bool TBL>
__device__ __forceinline__ void gemm_core(
    short* sW, int bid, int nrows, const ushort_t* __restrict__ agg,
    const ushort_t* self, const ushort_t* __restrict__ wswz,
    const float* __restrict__ bias, const float* __restrict__ tbl27,
    const int* __restrict__ x1, ushort_t* out) {
  constexpr int K = KM + KS;
  constexpr int NKT = K / 16;
  {
    const uint4* g4 = (const uint4*)wswz;
    uint4* s4 = (uint4*)sW;
    for (int i = threadIdx.x; i < K * 16; i += 256) s4[i] = g4[i];
  }
  __syncthreads();

  int wave = threadIdx.x >> 6, lane = threadIdx.x & 63;
  int r0 = bid * 256 + wave * 64;
  int qk = (lane >> 5) << 3;

  int ra = r0 + (lane & 31), rb = ra + 32;
  int rac = (ra < nrows) ? ra : 0, rbc = (rb < nrows) ? rb : 0;

  f32x16 acc[2][4];
#pragma unroll
  for (int rt = 0; rt < 2; ++rt)
#pragma unroll
    for (int ct = 0; ct < 4; ++ct) acc[rt][ct] = (f32x16)0.0f;

  const short8* sWv = (const short8*)sW;

#pragma unroll
  for (int kt = 0; kt < NKT; ++kt) {
    int k0 = kt * 16 + qk;
    short8 af, bf;
    if (kt * 16 < KM) {
      af = *((const short8*)(agg + (size_t)rac * KM + k0));
      bf = *((const short8*)(agg + (size_t)rbc * KM + k0));
    } else {
      af = *((const short8*)(self + (size_t)rac * SSTR + (k0 - KM)));
      bf = *((const short8*)(self + (size_t)rbc * SSTR + (k0 - KM)));
    }
#pragma unroll
    for (int ct = 0; ct < 4; ++ct) {
      short8 wf = sWv[(ct * NKT + kt) * 64 + lane];
      acc[0][ct] = __builtin_amdgcn_mfma_f32_32x32x16_bf16(af, wf, acc[0][ct], 0, 0, 0);
      acc[1][ct] = __builtin_amdgcn_mfma_f32_32x32x16_bf16(bf, wf, acc[1][ct], 0, 0, 0);
    }
  }

  int nloc = lane & 31;
  float bn[4];
#pragma unroll
  for (int ct = 0; ct < 4; ++ct) bn[ct] = bias[ct * 32 + nloc];
  int rowq = 4 * (lane >> 5);
#pragma unroll
  for (int rt = 0; rt < 2; ++rt) {
#pragma unroll
    for (int reg = 0; reg < 16; ++reg) {
      int row = r0 + rt * 32 + (reg & 3) + 8 * (reg >> 2) + rowq;
      if (row < nrows) {
        const float* tp = nullptr;
        if (TBL) {
          int a = x1[2 * row], g = x1[2 * row + 1];
          tp = tbl27 + (a * 3 + g) * 128 + nloc;
        }
#pragma unroll
        for (int ct = 0; ct < 4; ++ct) {
          float v = acc[rt][ct][reg] + bn[ct];
          if (TBL) v += tp[ct * 32];
          out[(size_t)row * 128 + ct * 32 + nloc] = f2bf(fmaxf(v, 0.0f));
        }
      }
    }
  }
}

// merged layer-1 GEMM: blocks [0,NUBG) user (K=128), [NUBG,+NSBG) seller (K=144)
__global__ __launch_bounds__(256, 2) void gemm1_k(
    const ushort_t* __restrict__ aggU, const ushort_t* __restrict__ aggS,
    const ushort_t* __restrict__ xu16, const ushort_t* __restrict__ xs16,
    const ushort_t* __restrict__ z1u, const ushort_t* __restrict__ z1s,
    const float* __restrict__ b1u, const float* __restrict__ b1s,
    const float* __restrict__ tbl27, const int* __restrict__ x1,
    ushort_t* __restrict__ ub, ushort_t* __restrict__ sb) {
  extern __shared__ short smem[];
  if (blockIdx.x < NUBG)
    gemm_core<64, 64, 64, true>(smem, blockIdx.x, NU_N, aggU, xu16, z1u, b1u, tbl27, x1, ub);
  else
    gemm_core<80, 64, 64, false>(smem, blockIdx.x - NUBG, NS_N, aggS, xs16, z1s, b1s,
                                 nullptr, nullptr, sb);
}

// merged layer-2 GEMM (both K=256, in-place)
__global__ __launch_bounds__(256, 2) void gemm2_k(
    const ushort_t* __restrict__ aggU, const ushort_t* __restrict__ aggS,
    const ushort_t* __restrict__ z2u, const ushort_t* __restrict__ z2s,
    const float* __restrict__ b2u, const float* __restrict__ b2s,
    ushort_t* ub, ushort_t* sb) {
  extern __shared__ short smem[];
  if (blockIdx.x < NUBG)
    gemm_core<128, 128, 128, false>(smem, blockIdx.x, NU_N, aggU, ub, z2u, b2u,
                                    nullptr, nullptr, ub);
  else
    gemm_core<128, 128, 128, false>(smem, blockIdx.x - NUBG, NS_N, aggS, sb, z2s, b2s,
                                    nullptr, nullptr, sb);
}

// ===================== final =====================
__global__ void final_k(const ushort_t* __restrict__ u2, const ushort_t* __restrict__ s2,
                        const int* __restrict__ mu, const int* __restrict__ ms,
                        const float* __restrict__ lw, const float* __restrict__ lb,
                        float* __restrict__ out) {
  int w = (blockIdx.x * blockDim.x + threadIdx.x) >> 6;
  int lane = threadIdx.x & 63;
  if (w >= M_N) return;
  int iu = mu[w], is = ms[w];
  uint_t a = ((const uint_t*)(u2 + (size_t)iu * 128))[lane];
  uint_t b = ((const uint_t*)(s2 + (size_t)is * 128))[lane];
  float p = bf2f(a & 0xffffu) * lw[2 * lane] + bf2f(a >> 16) * lw[2 * lane + 1]
          + bf2f(b & 0xffffu) * lw[128 + 2 * lane] + bf2f(b >> 16) * lw[129 + 2 * lane];
#pragma unroll
  for (int off = 32; off > 0; off >>= 1) p += __shfl_down(p, off, 64);
  if (lane == 0) out[w] = 1.0f / (1.0f + expf(-(p + lb[0])));
}

extern "C" void kernel_launch(void* const* d_in, const int* in_sizes, int n_in,
                              void* d_out, int out_size, void* d_ws, size_t ws_size,
                              hipStream_t stream) {
  const float* xu   = (const float*)d_in[0];
  const float* xs   = (const float*)d_in[1];
  const int*   x1   = (const int*)d_in[2];
  const int*   su   = (const int*)d_in[3];
  const int*   ds   = (const int*)d_in[4];
  const int*   ss   = (const int*)d_in[5];
  const int*   du   = (const int*)d_in[6];
  const int*   mu   = (const int*)d_in[7];
  const int*   ms   = (const int*)d_in[8];
  const float* age  = (const float*)d_in[9];
  const float* gen  = (const float*)d_in[10];
  const float* W1ul = (const float*)d_in[11];
  const float* W1ur = (const float*)d_in[12];
  const float* b1u  = (const float*)d_in[13];
  const float* W1sl = (const float*)d_in[14];
  const float* W1sr = (const float*)d_in[15];
  const float* b1s  = (const float*)d_in[16];
  const float* W2ul = (const float*)d_in[17];
  const float* W2ur = (const float*)d_in[18];
  const float* b2u  = (const float*)d_in[19];
  const float* W2sl = (const float*)d_in[20];
  const float* W2sr = (const float*)d_in[21];
  const float* b2s  = (const float*)d_in[22];
  const float* lw   = (const float*)d_in[23];
  const float* lb   = (const float*)d_in[24];

  char* w = (char*)d_ws;
  ushort_t* aggU = (ushort_t*)(w + OFF_AGGU);
  ushort_t* aggS = (ushort_t*)(w + OFF_AGGS);
  ushort_t* ub   = (ushort_t*)(w + OFF_U);
  ushort_t* sb   = (ushort_t*)(w + OFF_S);
  ushort_t* xu16 = (ushort_t*)(w + OFF_XU16);
  ushort_t* xs16 = (ushort_t*)(w + OFF_XS16);
  float* tbl27   = (float*)(w + OFF_TBL27);
  ushort_t* z1u  = (ushort_t*)(w + OFF_Z1U);
  ushort_t* z1s  = (ushort_t*)(w + OFF_Z1S);
  ushort_t* z2u  = (ushort_t*)(w + OFF_Z2U);
  ushort_t* z2s  = (ushort_t*)(w + OFF_Z2S);
  int* rpU    = (int*)(w + OFF_RPU);
  int* rpS    = (int*)(w + OFF_RPS);
  int* csrU   = (int*)(w + OFF_CSRU);
  int* csrS   = (int*)(w + OFF_CSRS);
  int2* tmpU  = (int2*)(w + OFF_TMPU);
  int2* tmpS  = (int2*)(w + OFF_TMPS);
  int* cmatU  = (int*)(w + OFF_CMU);
  int* cmatS  = (int*)(w + OFF_CMS);
  int* cmatUs = (int*)(w + OFF_CMUS);
  int* cmatSs = (int*)(w + OFF_CMSS);
  ushort_t* oh12 = (ushort_t*)(w + OFF_U);  // aliases ub pre-gemm1
  int* part   = (int*)(w + OFF_PART);
  float* out = (float*)d_out;

  // ---- merged prep + CSR hist (independent work, 1 dispatch) ----
  prep_hist_k<<<2 * NCH + PREPB, 256, 0, stream>>>(
      xu, xs, x1, age, gen, W1ul, W1ur, W1sl, W1sr, W2ul, W2ur, W2sl, W2sr,
      xu16, xs16, ub, sb, oh12, tbl27, z1u, z1s, z2u, z2s,
      du, ds, cmatU, cmatS);

  // ---- CSR build: LDS counting sort, zero global atomics ----
  scan1_k<<<2 * NCB, 256, 0, stream>>>(cmatU, cmatS, cmatUs, cmatSs, part);
  scan3_k<<<2 * NCB, 256, 0, stream>>>(cmatUs, cmatSs, part);
  scatter_k<<<2 * NCH, 256, 0, stream>>>(du, ds, su, ss, cmatUs, cmatSs, tmpU, tmpS);
  build_k<<<2 * NBKT, 256, 0, stream>>>(cmatUs, cmatSs, tmpU, tmpS,
                                        rpU, rpS, csrU, csrS);

  // ---- layer 1 ----
  gather1_k<<<9375, 256, 0, stream>>>(rpU, csrU, xs16, rpS, csrS, xu16, oh12,
                                      aggU, aggS);
  gemm1_k<<<NUBG + NSBG, 256, 144 * 128 * 2, stream>>>(aggU, aggS, xu16, xs16, z1u, z1s,
                                                       b1u, b1s, tbl27, x1, ub, sb);

  // ---- layer 2 ----
  gather2_k<<<15625, 256, 0, stream>>>(rpU, csrU, sb, rpS, csrS, ub, aggU, aggS);
  gemm2_k<<<NUBG + NSBG, 256, 256 * 128 * 2, stream>>>(aggU, aggS, z2u, z2s,
                                                       b2u, b2s, ub, sb);

  // ---- final linear + sigmoid ----
  final_k<<<(M_N * 64 + 255) / 256, 256, 0, stream>>>(ub, sb, mu, ms, lw, lb, out);
}